// Round 18
// baseline (119.268 us; speedup 1.0000x reference)
//
#include <hip/hip_runtime.h>
#include <math.h>

#define NB 4
#define NN 6000
#define NC 91
#define NG 32
#define NK 100
#define NCLS (NC - 1)        /* 90 */
#define NBUC (NB * NCLS)     /* 360 */
#define PMAX 512             /* fast-path bucket capacity */
#define MATW 256             /* suppression-matrix prefix width */
#define MPB 4096             /* merge stage-B capacity per image */
#define RS_BLOCKS 6000       /* 24000 rows / 4 waves per block */

#define SCORE_TH 0.05f
#define NMS_TH 0.5f
#define MATCH_TH 0.5f
#define MIN_SIZE 0.01f
#define BBOX_CLIP 4.135166556742356f  /* log(1000/16) */
/* fdiv_rn(inter,den) > 0.5f  <=>  (double)inter > C_SUP*(double)den  (exact) */
#define C_SUP 0.5000000298023223876953125

#define CFENCE() asm volatile("" ::: "memory")

// ---------------- decode (identical op sequence to rounds 1-17) ------------
__device__ __forceinline__ bool decode_one(
    const float* __restrict__ reg, const float* __restrict__ props,
    float l, float m, float s0, int row, int c, float out[5])
{
    float score = __fdiv_rn(expf(__fsub_rn(l, m)), s0);

    const float4 p = *reinterpret_cast<const float4*>(props + (size_t)row * 4);
    float w  = __fsub_rn(p.z, p.x);
    float h  = __fsub_rn(p.w, p.y);
    float cx = __fadd_rn(p.x, __fmul_rn(0.5f, w));
    float cy = __fadd_rn(p.y, __fmul_rn(0.5f, h));

    const float4 r4 = *reinterpret_cast<const float4*>(
        reg + (size_t)row * (NC * 4) + (size_t)c * 4);
    float dx = __fdiv_rn(r4.x, 10.0f);
    float dy = __fdiv_rn(r4.y, 10.0f);
    float dw = fminf(__fdiv_rn(r4.z, 5.0f), BBOX_CLIP);
    float dh = fminf(__fdiv_rn(r4.w, 5.0f), BBOX_CLIP);

    float pcx = __fadd_rn(__fmul_rn(dx, w), cx);
    float pcy = __fadd_rn(__fmul_rn(dy, h), cy);
    float pw  = __fmul_rn(expf(dw), w);
    float ph  = __fmul_rn(expf(dh), h);

    float x1 = __fsub_rn(pcx, __fmul_rn(0.5f, pw));
    float y1 = __fsub_rn(pcy, __fmul_rn(0.5f, ph));
    float x2 = __fadd_rn(pcx, __fmul_rn(0.5f, pw));
    float y2 = __fadd_rn(pcy, __fmul_rn(0.5f, ph));
    x1 = fminf(fmaxf(x1, 0.0f), 800.0f);
    y1 = fminf(fmaxf(y1, 0.0f), 800.0f);
    x2 = fminf(fmaxf(x2, 0.0f), 800.0f);
    y2 = fminf(fmaxf(y2, 0.0f), 800.0f);

    out[0] = score; out[1] = x1; out[2] = y1; out[3] = x2; out[4] = y2;
    float ws_ = __fsub_rn(x2, x1);
    float hs_ = __fsub_rn(y2, y1);
    return (score > SCORE_TH) && (ws_ >= MIN_SIZE) && (hs_ >= MIN_SIZE);
}

// ---- fused: softmax stats + prefilter + DETERMINISTIC-SLOT fill | matcher -
// entry record (8 floats, 32B): x1,y1,x2,y2,score,id,pad,pad @ slot = nprop
__global__ __launch_bounds__(256) void fused_kernel(
    const float* __restrict__ logits, const float* __restrict__ reg,
    const float* __restrict__ props, const float* __restrict__ gtb,
    const int* __restrict__ gtl,
    float* __restrict__ out_assigned, float* __restrict__ out_matched,
    unsigned char* __restrict__ flags, float* __restrict__ ent)
{
    int bid = blockIdx.x;
    if (bid < RS_BLOCKS) {
        int wid = threadIdx.x >> 6, lane = threadIdx.x & 63;
        int row = bid * 4 + wid;                 // [0, 24000)
        const float* rp = logits + (size_t)row * NC;
        float l0 = rp[lane];
        float l1 = (lane < NC - 64) ? rp[64 + lane] : -INFINITY;
        float m = fmaxf(fmaxf(-INFINITY, l0), l1);
        for (int o = 32; o; o >>= 1) m = fmaxf(m, __shfl_down(m, o));
        m = __shfl(m, 0);
        float s = __fadd_rn(__fadd_rn(0.0f, expf(__fsub_rn(l0, m))),
                            expf(__fsub_rn(l1, m)));   // exp(-inf)=0 exact
        for (int o = 32; o; o >>= 1) s = __fadd_rn(s, __shfl_down(s, o));
        float s0 = __shfl(s, 0);
        // conservative prefilter: score>0.05 => l > m + log(0.04*s)
        float thr = __fadd_rn(m, logf(__fmul_rn(0.04f, s0)));

        int b = row / NN;
        int nprop = row - b * NN;

        if (lane >= 1 && l0 > thr) {
            float o[5];
            if (decode_one(reg, props, l0, m, s0, row, lane, o)) {
                int g = b * NCLS + (lane - 1);
                size_t sl = (size_t)g * NN + nprop;
                float* e = ent + sl * 8;
                *reinterpret_cast<float4*>(e) =
                    make_float4(o[1], o[2], o[3], o[4]);
                *reinterpret_cast<float2*>(e + 4) =
                    make_float2(o[0], (float)(nprop * NCLS + (lane - 1)));
                flags[sl] = 1;
            }
        }
        if (lane < NC - 64 && l1 > thr) {
            float o[5];
            int c = lane + 64;
            if (decode_one(reg, props, l1, m, s0, row, c, o)) {
                int g = b * NCLS + (c - 1);
                size_t sl = (size_t)g * NN + nprop;
                float* e = ent + sl * 8;
                *reinterpret_cast<float4*>(e) =
                    make_float4(o[1], o[2], o[3], o[4]);
                *reinterpret_cast<float2*>(e + 4) =
                    make_float2(o[0], (float)(nprop * NCLS + (c - 1)));
                flags[sl] = 1;
            }
        }
    } else {
        // ---- matcher blocks ----
        int t = (bid - RS_BLOCKS) * 256 + threadIdx.x;
        if (t >= NB * NN) return;
        int b = t / NN;
        const float4 p = *reinterpret_cast<const float4*>(props + (size_t)t * 4);
        float parea = __fmul_rn(__fsub_rn(p.z, p.x), __fsub_rn(p.w, p.y));
        float best = -1.0f; int bi = -1;
        for (int g = 0; g < NG; ++g) {
            const float4 q = *reinterpret_cast<const float4*>(gtb + ((size_t)b * NG + g) * 4);
            float garea = __fmul_rn(__fsub_rn(q.z, q.x), __fsub_rn(q.w, q.y));
            float ltx = fmaxf(q.x, p.x), lty = fmaxf(q.y, p.y);
            float rbx = fminf(q.z, p.z), rby = fminf(q.w, p.w);
            float wx = fmaxf(__fsub_rn(rbx, ltx), 0.0f);
            float wy = fmaxf(__fsub_rn(rby, lty), 0.0f);
            float inter = __fmul_rn(wx, wy);
            float iou = __fdiv_rn(inter, __fsub_rn(__fadd_rn(garea, parea), inter));
            if (iou > best) { best = iou; bi = g; }
        }
        int matched = (best >= MATCH_TH) ? bi : -1;
        int assigned = (matched >= 0) ? gtl[b * NG + matched] : 0;
        out_matched[t]  = (float)matched;
        out_assigned[t] = (float)assigned;
    }
}

// -------- sparse exact fallback for n_total > PMAX (never expected) --------
__device__ void nms_glb_sparse(int g, const unsigned char* __restrict__ F,
                               float* __restrict__ E, float tb, float cls,
                               float* __restrict__ selbuf, int* __restrict__ selcnt)
{
    int lane = threadIdx.x & 63;
    int kout = 0;
    for (int k = 0; k < NK; ++k) {
        float bv = -INFINITY, boi = INFINITY; int bi = -1;
        for (int i = lane; i < NN; i += 64) {
            if (!F[i]) continue;
            float v = E[(size_t)i * 8 + 4], oi = E[(size_t)i * 8 + 5];
            if (v > bv || (v == bv && oi < boi)) { bv = v; boi = oi; bi = i; }
        }
        int wl = lane;
        for (int o = 1; o < 64; o <<= 1) {
            float v2 = __shfl_xor(bv, o); float o2 = __shfl_xor(boi, o);
            int l2 = __shfl_xor(wl, o);
            bool bt = (v2 > bv) || (v2 == bv && o2 < boi);
            bv = bt ? v2 : bv; boi = bt ? o2 : boi; wl = bt ? l2 : wl;
        }
        if (bv == -INFINITY) break;
        int wi = __shfl(bi, wl);
        float sx1 = E[(size_t)wi * 8 + 0], sy1 = E[(size_t)wi * 8 + 1];
        float sx2 = E[(size_t)wi * 8 + 2], sy2 = E[(size_t)wi * 8 + 3];
        if (lane == wl) {
            float* so = selbuf + ((size_t)g * NK + k) * 8;
            so[0] = bv; so[1] = sx1; so[2] = sy1; so[3] = sx2; so[4] = sy2;
            so[5] = cls; so[6] = boi; so[7] = 0.0f;
        }
        float bx1 = __fadd_rn(sx1, tb), by1 = __fadd_rn(sy1, tb);
        float bx2 = __fadd_rn(sx2, tb), by2 = __fadd_rn(sy2, tb);
        float sar = __fmul_rn(__fsub_rn(bx2, bx1), __fsub_rn(by2, by1));
        for (int i = lane; i < NN; i += 64) {
            if (!F[i]) continue;
            float v = E[(size_t)i * 8 + 4];
            if (v == -INFINITY) continue;
            float ox1 = __fadd_rn(E[(size_t)i * 8 + 0], tb);
            float oy1 = __fadd_rn(E[(size_t)i * 8 + 1], tb);
            float ox2 = __fadd_rn(E[(size_t)i * 8 + 2], tb);
            float oy2 = __fadd_rn(E[(size_t)i * 8 + 3], tb);
            float oar = __fmul_rn(__fsub_rn(ox2, ox1), __fsub_rn(oy2, oy1));
            float ltx = fmaxf(ox1, bx1), lty = fmaxf(oy1, by1);
            float rbx = fminf(ox2, bx2), rby = fminf(oy2, by2);
            float wx = fmaxf(__fsub_rn(rbx, ltx), 0.0f);
            float wy = fmaxf(__fsub_rn(rby, lty), 0.0f);
            float inter = __fmul_rn(wx, wy);
            float den = __fsub_rn(__fadd_rn(oar, sar), inter);
            if ((double)inter > C_SUP * (double)den) E[(size_t)i * 8 + 4] = -INFINITY;
        }
        kout = k + 1;
    }
    if (lane == 0) selcnt[g] = kout;
}

template <int CAP>
__device__ __forceinline__ float selN(const float a[CAP], int j) {
    float r = a[0];
#pragma unroll
    for (int i = 1; i < CAP; ++i) r = (j == i) ? a[i] : r;
    return r;
}
__device__ __forceinline__ float rdlane(float v, int l) {
    return __uint_as_float(
        (unsigned)__builtin_amdgcn_readlane((int)__float_as_uint(v), l));
}
__device__ __forceinline__ unsigned long long rdlane64(unsigned long long v, int l) {
    unsigned lo = (unsigned)__builtin_amdgcn_readlane((int)(unsigned)v, l);
    unsigned hi = (unsigned)__builtin_amdgcn_readlane((int)(unsigned)(v >> 32), l);
    return ((unsigned long long)hi << 32) | lo;
}

// exact register sweep (fallback; identical semantics to round-10 main path)
template <int CAP>
__device__ __forceinline__ int sweep_reg(
    int lane, int n, float tb,
    const float* sx1, const float* sy1, const float* sx2, const float* sy2,
    int* acc)
{
    float ox1[CAP], oy1[CAP], ox2[CAP], oy2[CAP], oar[CAP];
    unsigned alive = 0;
#pragma unroll
    for (int j = 0; j < CAP; ++j) {
        int sidx = lane * CAP + j;
        if (sidx < n) {
            float a  = __fadd_rn(sx1[sidx], tb);
            float b_ = __fadd_rn(sy1[sidx], tb);
            float c_ = __fadd_rn(sx2[sidx], tb);
            float d_ = __fadd_rn(sy2[sidx], tb);
            ox1[j] = a; oy1[j] = b_; ox2[j] = c_; oy2[j] = d_;
            oar[j] = __fmul_rn(__fsub_rn(c_, a), __fsub_rn(d_, b_));
            alive |= 1u << j;
        } else {
            ox1[j] = 0.f; oy1[j] = 0.f; ox2[j] = 0.f; oy2[j] = 0.f; oar[j] = 0.f;
        }
    }
    int kout = 0;
    while (kout < NK) {
        unsigned long long bal = __ballot(alive != 0u);
        if (!bal) break;
        int fl = (int)__ffsll(bal) - 1;                           // uniform
        unsigned am = (unsigned)__builtin_amdgcn_readlane((int)alive, fl);
        int js = __ffs(am) - 1;                                   // uniform
        float bx1 = rdlane(selN<CAP>(ox1, js), fl);
        float by1 = rdlane(selN<CAP>(oy1, js), fl);
        float bx2 = rdlane(selN<CAP>(ox2, js), fl);
        float by2 = rdlane(selN<CAP>(oy2, js), fl);
        float bar = rdlane(selN<CAP>(oar, js), fl);
        if (lane == 0) acc[kout] = fl * CAP + js;
        kout++;
        unsigned kill = 0;
#pragma unroll
        for (int j = 0; j < CAP; ++j) {
            float ltx = fmaxf(ox1[j], bx1), lty = fmaxf(oy1[j], by1);
            float rbx = fminf(ox2[j], bx2), rby = fminf(oy2[j], by2);
            float wx = fmaxf(__fsub_rn(rbx, ltx), 0.0f);
            float wy = fmaxf(__fsub_rn(rby, lty), 0.0f);
            float inter = __fmul_rn(wx, wy);
            float den = __fsub_rn(__fadd_rn(oar[j], bar), inter);
            if ((double)inter > C_SUP * (double)den) kill |= 1u << j;
        }
        alive &= ~kill;
    }
    return kout;
}

// -- 512-thr: flag-scan compaction + sort + ballot matrix + scalar sweep ----
__global__ __launch_bounds__(512) void bucket_nms_kernel(
    const unsigned char* __restrict__ flags,
    float* __restrict__ entries,
    float* __restrict__ selbuf, int* __restrict__ selcnt)
{
    int g = blockIdx.x;
    int tid = threadIdx.x;
    float* E = entries + (size_t)g * NN * 8;
    const unsigned char* F = flags + (size_t)g * NN;
    float cls = (float)(g % NCLS + 1);
    float tb = __fmul_rn(cls, 801.0f);

    __shared__ int sidx[PMAX];
    __shared__ int s_n;
    __shared__ unsigned skhi[PMAX], sklo[PMAX];
    __shared__ int sperm[PMAX];
    __shared__ float sx1[PMAX], sy1[PMAX], sx2[PMAX], sy2[PMAX];
    __shared__ unsigned long long dmask[MATW * 4];   // 8 KB
    __shared__ int acc[NK];
    __shared__ int s_kout, s_fb;

    // phase 0: compact valid slots (coalesced flag scan; order normalized by sort)
    if (tid == 0) s_n = 0;
    __syncthreads();
    for (int i = tid; i < NN; i += 512) {
        if (F[i]) {
            int p = atomicAdd(&s_n, 1);
            if (p < PMAX) sidx[p] = i;
        }
    }
    __syncthreads();
    int ntot = s_n;
    if (ntot == 0) { if (tid == 0) selcnt[g] = 0; return; }
    if (ntot > PMAX) {   // never expected; exact sparse path
        if (tid < 64) nms_glb_sparse(g, F, E, tb, cls, selbuf, selcnt);
        return;
    }
    int n = ntot;

    int P = 64; while (P < n) P <<= 1;

    for (int i = tid; i < P; i += 512) {
        if (i < n) {
            const float2 kv = *reinterpret_cast<const float2*>(
                E + (size_t)sidx[i] * 8 + 4);
            skhi[i] = __float_as_uint(kv.x);
            sklo[i] = ~((unsigned)kv.y);   // u64 max == (score desc, idx asc)
        } else { skhi[i] = 0u; sklo[i] = 0u; }
        sperm[i] = i;
    }
    __syncthreads();
    // bitonic sort desc; j<128 stages wave-local
    for (int k = 2; k <= P; k <<= 1) {
        for (int j = k >> 1; j > 0; j >>= 1) {
            bool cross = (j >= 128);
            if (cross) __syncthreads();
            for (int t = tid; t < (P >> 1); t += 512) {
                int i = ((t & ~(j - 1)) << 1) | (t & (j - 1));
                int l = i | j;
                unsigned ah = skhi[i], al = sklo[i], ch = skhi[l], cl_ = sklo[l];
                bool alt = (ah < ch) || (ah == ch && al < cl_);
                bool agt = (ah > ch) || (ah == ch && al > cl_);
                bool sw = ((i & k) == 0) ? alt : agt;
                if (sw) {
                    skhi[i] = ch; sklo[i] = cl_; skhi[l] = ah; sklo[l] = al;
                    int tp = sperm[i]; sperm[i] = sperm[l]; sperm[l] = tp;
                }
            }
            if (cross) __syncthreads();
            else CFENCE();
        }
    }
    __syncthreads();
    // stage RAW coords in sorted order (one 16B load per entry)
    for (int i = tid; i < n; i += 512) {
        const float4 v = *reinterpret_cast<const float4*>(
            E + (size_t)sidx[sperm[i]] * 8);
        sx1[i] = v.x; sy1[i] = v.y; sx2[i] = v.z; sy2[i] = v.w;
    }
    __syncthreads();

    int W = (n < MATW) ? n : MATW;
    int nchunk = (W + 63) >> 6;
    int wv = tid >> 6, lane = tid & 63;

    // j-chunk boxes (offset coords) in registers
    float jx1[4], jy1[4], jx2[4], jy2[4], jar[4];
#pragma unroll
    for (int c = 0; c < 4; ++c) {
        int j = c * 64 + lane;
        if (j < W) {
            float a  = __fadd_rn(sx1[j], tb);
            float b_ = __fadd_rn(sy1[j], tb);
            float c_ = __fadd_rn(sx2[j], tb);
            float d_ = __fadd_rn(sy2[j], tb);
            jx1[c] = a; jy1[c] = b_; jx2[c] = c_; jy2[c] = d_;
            jar[c] = __fmul_rn(__fsub_rn(c_, a), __fsub_rn(d_, b_));
        } else {
            jx1[c] = 0.f; jy1[c] = 0.f; jx2[c] = 0.f; jy2[c] = 0.f; jar[c] = 0.f;
        }
    }
    // matrix rows striped across 8 waves; uniform LDS row read + prefetch
    {
        int i0 = wv;
        float nx1 = 0.f, ny1 = 0.f, nx2 = 0.f, ny2 = 0.f;
        if (i0 < W) { nx1 = sx1[i0]; ny1 = sy1[i0]; nx2 = sx2[i0]; ny2 = sy2[i0]; }
        for (int i = i0; i < W; i += 8) {
            float rx1 = nx1, ry1 = ny1, rx2 = nx2, ry2 = ny2;
            int ni = i + 8;
            if (ni < W) { nx1 = sx1[ni]; ny1 = sy1[ni]; nx2 = sx2[ni]; ny2 = sy2[ni]; }
            float bx1 = __fadd_rn(rx1, tb), by1 = __fadd_rn(ry1, tb);
            float bx2 = __fadd_rn(rx2, tb), by2 = __fadd_rn(ry2, tb);
            float bar = __fmul_rn(__fsub_rn(bx2, bx1), __fsub_rn(by2, by1));
            int ic = i >> 6;
#pragma unroll
            for (int c = 0; c < 4; ++c) {
                if (c >= ic && c < nchunk) {
                    bool jv = (c * 64 + lane) < W;
                    float ltx = fmaxf(jx1[c], bx1), lty = fmaxf(jy1[c], by1);
                    float rbx = fminf(jx2[c], bx2), rby = fminf(jy2[c], by2);
                    float wx = fmaxf(__fsub_rn(rbx, ltx), 0.0f);
                    float wy = fmaxf(__fsub_rn(rby, lty), 0.0f);
                    float inter = __fmul_rn(wx, wy);
                    float den = __fsub_rn(__fadd_rn(jar[c], bar), inter);
                    bool sup = jv && ((double)inter > C_SUP * (double)den);
                    unsigned long long w64 = __ballot(sup);
                    if (lane == 0) dmask[i * 4 + c] = w64;
                }
            }
        }
    }
    __syncthreads();

    // SCALAR bit sweep on wave 0 (wave-uniform alive words)
    if (tid < 64) {
        unsigned long long a0 = 0, a1 = 0, a2 = 0, a3 = 0;
        {
            int rem = W;
            a0 = (rem >= 64) ? ~0ull : ((rem > 0) ? ((1ull << rem) - 1) : 0); rem -= 64;
            a1 = (rem >= 64) ? ~0ull : ((rem > 0) ? ((1ull << rem) - 1) : 0); rem -= 64;
            a2 = (rem >= 64) ? ~0ull : ((rem > 0) ? ((1ull << rem) - 1) : 0); rem -= 64;
            a3 = (rem >= 64) ? ~0ull : ((rem > 0) ? ((1ull << rem) - 1) : 0);
        }
        int kout = 0;
        while (kout < NK) {
            int cand;
            if      (a0) cand = (int)__ffsll(a0) - 1;
            else if (a1) cand = 64  + (int)__ffsll(a1) - 1;
            else if (a2) cand = 128 + (int)__ffsll(a2) - 1;
            else if (a3) cand = 192 + (int)__ffsll(a3) - 1;
            else break;
            if (lane == 0) acc[kout] = cand;
            kout++;
            unsigned long long mrow = (lane < 4) ? dmask[cand * 4 + lane] : 0ull;
            a0 &= ~rdlane64(mrow, 0);
            a1 &= ~rdlane64(mrow, 1);
            a2 &= ~rdlane64(mrow, 2);
            a3 &= ~rdlane64(mrow, 3);
        }
        if (lane == 0) {
            s_kout = kout;
            s_fb = (kout < NK && n > W) ? 1 : 0;   // prefix exhausted early
        }
    }
    __syncthreads();

    if (s_fb) {
        // exact fallback (rare): redo from scratch with the register sweep
        if (tid < 64) {
            int kout = sweep_reg<8>(lane, n, tb, sx1, sy1, sx2, sy2, acc);
            if (lane == 0) s_kout = kout;
        }
        __syncthreads();
    }

    int kc = s_kout;
    if (tid == 0) selcnt[g] = kc;
    for (int k = tid; k < kc; k += 512) {
        int cand = acc[k];
        float* so = selbuf + ((size_t)g * NK + k) * 8;
        so[0] = __uint_as_float(skhi[cand]);
        so[1] = sx1[cand]; so[2] = sy1[cand];
        so[3] = sx2[cand]; so[4] = sy2[cand];
        so[5] = cls; so[6] = (float)(~sklo[cand]); so[7] = 0.0f;
    }
}

// ------ merge: exact parallel top-K via LB bound (unchanged from r13) ------
__global__ __launch_bounds__(512) void merge_kernel(
    const float* __restrict__ selbuf, const int* __restrict__ selcnt,
    float* __restrict__ out_dets, float* __restrict__ out_kl)
{
    int b = blockIdx.x, tid = threadIdx.x;
    __shared__ int scnt[NCLS], soff[NCLS + 1];
    __shared__ unsigned akhi[512], aklo[512];
    __shared__ unsigned bkhi[MPB], bklo[MPB], bpay[MPB];
    __shared__ int s_T, s_cntA;
    __shared__ unsigned s_LBhi, s_LBlo;

    if (tid < NCLS) scnt[tid] = selcnt[b * NCLS + tid];
    if (tid == 0) s_T = 0;
    __syncthreads();
    if (tid == 0) {
        int a = 0, ca = 0;
        for (int c = 0; c < NCLS; ++c) {
            soff[c] = a; a += scnt[c];
            ca += (scnt[c] < 4 ? scnt[c] : 4);
        }
        soff[NCLS] = a; s_cntA = ca;
    }
    __syncthreads();
    int tot = soff[NCLS];

    if (tot == 0) {
        for (int z = tid; z < NK * 5; z += 512) out_dets[(size_t)b * NK * 5 + z] = 0.0f;
        for (int z = tid; z < NK; z += 512)     out_kl[(size_t)b * NK + z] = -1.0f;
        return;
    }

    {
        unsigned kh = 0u, kl = 0u;
        if (tid < NCLS * 4) {
            int c = tid >> 2, i = tid & 3;
            if (i < scnt[c]) {
                const float* e = selbuf + ((size_t)(b * NCLS + c) * NK + i) * 8;
                kh = __float_as_uint(e[0]); kl = ~((unsigned)e[6]);
            }
        }
        akhi[tid] = kh; aklo[tid] = kl;
    }
    __syncthreads();
    for (int k = 2; k <= 512; k <<= 1) {
        for (int j = k >> 1; j > 0; j >>= 1) {
            bool cross = (j >= 128);
            if (cross) __syncthreads();
            if (tid < 256) {
                int t = tid;
                int i = ((t & ~(j - 1)) << 1) | (t & (j - 1));
                int l = i | j;
                unsigned ah = akhi[i], al = aklo[i], ch = akhi[l], cl_ = aklo[l];
                bool alt = (ah < ch) || (ah == ch && al < cl_);
                bool agt = (ah > ch) || (ah == ch && al > cl_);
                bool sw = ((i & k) == 0) ? alt : agt;
                if (sw) {
                    akhi[i] = ch; aklo[i] = cl_; akhi[l] = ah; aklo[l] = al;
                }
            }
            if (cross) __syncthreads();
            else CFENCE();
        }
    }
    __syncthreads();
    if (tid == 0) {
        if (s_cntA >= NK) { s_LBhi = akhi[NK - 1]; s_LBlo = aklo[NK - 1]; }
        else              { s_LBhi = 0u;           s_LBlo = 0u; }
    }
    __syncthreads();
    unsigned LBhi = s_LBhi, LBlo = s_LBlo;

    for (int flat = tid; flat < tot; flat += 512) {
        int lo = 0, hi = NCLS - 1;
        while (lo < hi) { int mid = (lo + hi + 1) >> 1;
                          if (soff[mid] <= flat) lo = mid; else hi = mid - 1; }
        int c = lo, i = flat - soff[c];
        const float* e = selbuf + ((size_t)(b * NCLS + c) * NK + i) * 8;
        unsigned kh = __float_as_uint(e[0]), kl = ~((unsigned)e[6]);
        bool ge = (kh > LBhi) || (kh == LBhi && kl >= LBlo);
        if (ge) {
            int pos = atomicAdd(&s_T, 1);
            if (pos < MPB) { bkhi[pos] = kh; bklo[pos] = kl;
                             bpay[pos] = (unsigned)((c << 7) | i); }
        }
    }
    __syncthreads();
    int T = s_T;

    if (T > MPB) {
        if (tid >= 64) return;
        int lane = tid;
        int g0 = b * NCLS + lane;
        int g1 = (lane < NCLS - 64) ? g0 + 64 : -1;
        int c0 = scnt[lane];
        int c1 = (g1 >= 0) ? scnt[lane + 64] : 0;
        int p0 = 0, p1 = 0;
        unsigned long long k0c = 0, k1c = 0;
        if (p0 < c0) { const float* h = selbuf + ((size_t)g0 * NK) * 8;
            k0c = ((unsigned long long)__float_as_uint(h[0]) << 32) | (unsigned long long)(~(unsigned)h[6]); }
        if (g1 >= 0 && p1 < c1) { const float* h = selbuf + ((size_t)g1 * NK) * 8;
            k1c = ((unsigned long long)__float_as_uint(h[0]) << 32) | (unsigned long long)(~(unsigned)h[6]); }
        for (int k = 0; k < NK; ++k) {
            bool t1 = (k1c > k0c);
            unsigned long long bk = t1 ? k1c : k0c;
            int bslot = t1 ? (lane + 64) : lane;
            for (int o = 1; o < 64; o <<= 1) {
                unsigned long long k2 = __shfl_xor(bk, o);
                int b2 = __shfl_xor(bslot, o);
                if (k2 > bk) { bk = k2; bslot = b2; }
            }
            if (bk == 0ull) {
                for (int z = k * 5 + lane; z < NK * 5; z += 64)
                    out_dets[(size_t)b * NK * 5 + z] = 0.0f;
                for (int z = k + lane; z < NK; z += 64)
                    out_kl[(size_t)b * NK + z] = -1.0f;
                return;
            }
            int owner = bslot & 63;
            if (lane == owner) {
                bool isA = (bslot < 64);
                int gg = isA ? g0 : g1;
                int pp = isA ? p0 : p1;
                const float* e = selbuf + ((size_t)gg * NK + pp) * 8;
                size_t o = ((size_t)b * NK + k) * 5;
                out_dets[o + 0] = e[1]; out_dets[o + 1] = e[2];
                out_dets[o + 2] = e[3]; out_dets[o + 3] = e[4];
                out_dets[o + 4] = e[0];
                out_kl[(size_t)b * NK + k] = e[5];
                if (isA) {
                    p0++; k0c = 0;
                    if (p0 < c0) { const float* h = selbuf + ((size_t)g0 * NK + p0) * 8;
                        k0c = ((unsigned long long)__float_as_uint(h[0]) << 32) | (unsigned long long)(~(unsigned)h[6]); }
                } else {
                    p1++; k1c = 0;
                    if (p1 < c1) { const float* h = selbuf + ((size_t)g1 * NK + p1) * 8;
                        k1c = ((unsigned long long)__float_as_uint(h[0]) << 32) | (unsigned long long)(~(unsigned)h[6]); }
                }
            }
        }
        return;
    }

    int P = 128; while (P < T) P <<= 1;
    for (int i = T + tid; i < P; i += 512) { bkhi[i] = 0u; bklo[i] = 0u; bpay[i] = 0u; }
    __syncthreads();
    for (int k = 2; k <= P; k <<= 1) {
        for (int j = k >> 1; j > 0; j >>= 1) {
            bool cross = (j >= 128);
            if (cross) __syncthreads();
            for (int t = tid; t < (P >> 1); t += 512) {
                int i = ((t & ~(j - 1)) << 1) | (t & (j - 1));
                int l = i | j;
                unsigned ah = bkhi[i], al = bklo[i], ch = bkhi[l], cl_ = bklo[l];
                bool alt = (ah < ch) || (ah == ch && al < cl_);
                bool agt = (ah > ch) || (ah == ch && al > cl_);
                bool sw = ((i & k) == 0) ? alt : agt;
                if (sw) {
                    bkhi[i] = ch; bklo[i] = cl_; bkhi[l] = ah; bklo[l] = al;
                    unsigned tp = bpay[i]; bpay[i] = bpay[l]; bpay[l] = tp;
                }
            }
            if (cross) __syncthreads();
            else CFENCE();
        }
    }
    __syncthreads();
    int kc = (T < NK) ? T : NK;
    for (int k = tid; k < NK; k += 512) {
        size_t o = ((size_t)b * NK + k) * 5;
        if (k < kc) {
            unsigned pay = bpay[k];
            int c = (int)(pay >> 7), p = (int)(pay & 127);
            const float* e = selbuf + ((size_t)(b * NCLS + c) * NK + p) * 8;
            out_dets[o + 0] = e[1]; out_dets[o + 1] = e[2];
            out_dets[o + 2] = e[3]; out_dets[o + 3] = e[4];
            out_dets[o + 4] = e[0];
            out_kl[(size_t)b * NK + k] = e[5];
        } else {
            out_dets[o + 0] = 0.0f; out_dets[o + 1] = 0.0f;
            out_dets[o + 2] = 0.0f; out_dets[o + 3] = 0.0f;
            out_dets[o + 4] = 0.0f;
            out_kl[(size_t)b * NK + k] = -1.0f;
        }
    }
}

extern "C" void kernel_launch(void* const* d_in, const int* in_sizes, int n_in,
                              void* d_out, int out_size, void* d_ws, size_t ws_size,
                              hipStream_t stream) {
    const float* logits = (const float*)d_in[0];
    const float* reg    = (const float*)d_in[1];
    const float* props  = (const float*)d_in[2];
    const float* gtb    = (const float*)d_in[3];
    const int*   gtl    = (const int*)d_in[4];

    float* out          = (float*)d_out;
    float* out_dets     = out;                    // NB*NK*5 = 2000
    float* out_kl       = out + NB * NK * 5;      // NB*NK   = 400
    float* out_assigned = out_kl + NB * NK;       // NB*NN   = 24000
    float* out_matched  = out_assigned + NB * NN; // NB*NN   = 24000

    char* ws = (char*)d_ws;
    int*   selcnt  = (int*)(ws + 0);                      // 1440 B
    float* selbuf  = (float*)(ws + 65536);                // 1152000 B
    unsigned char* flags = (unsigned char*)(ws + 2097152);// 360*6000 = 2.16 MB
    float* entries = (float*)(ws + 8388608);              // 360*6000*32B = 69.1 MB

    hipMemsetAsync(flags, 0, (size_t)NBUC * NN, stream);
    const int MATCH_BLOCKS = (NB * NN + 255) / 256;   // 94
    fused_kernel<<<RS_BLOCKS + MATCH_BLOCKS, 256, 0, stream>>>(
        logits, reg, props, gtb, gtl, out_assigned, out_matched,
        flags, entries);
    bucket_nms_kernel<<<NBUC, 512, 0, stream>>>(
        flags, entries, selbuf, selcnt);
    merge_kernel<<<NB, 512, 0, stream>>>(selbuf, selcnt, out_dets, out_kl);
}

// Round 19
// 115.761 us; speedup vs baseline: 1.0303x; 1.0303x over previous
//
#include <hip/hip_runtime.h>
#include <math.h>

#define NB 4
#define NN 6000
#define NC 91
#define NG 32
#define NK 100
#define NCLS (NC - 1)        /* 90 */
#define NBUC (NB * NCLS)     /* 360 */
#define NWRD 94              /* ceil(NN/64) validity-mask words per bucket */
#define NWRD_P 96            /* padded stride */
#define PMAX 512             /* fast-path bucket capacity */
#define MATW 256             /* suppression-matrix prefix width */
#define MPB 4096             /* merge stage-B capacity per image */
#define RS_BLOCKS 6000       /* 24000 rows / 4 waves per block */

#define SCORE_TH 0.05f
#define NMS_TH 0.5f
#define MATCH_TH 0.5f
#define MIN_SIZE 0.01f
#define BBOX_CLIP 4.135166556742356f  /* log(1000/16) */
/* fdiv_rn(inter,den) > 0.5f  <=>  (double)inter > C_SUP*(double)den  (exact) */
#define C_SUP 0.5000000298023223876953125

#define CFENCE() asm volatile("" ::: "memory")

// ---------------- decode (identical op sequence to rounds 1-18) ------------
__device__ __forceinline__ bool decode_one(
    const float* __restrict__ reg, const float* __restrict__ props,
    float l, float m, float s0, int row, int c, float out[5])
{
    float score = __fdiv_rn(expf(__fsub_rn(l, m)), s0);

    const float4 p = *reinterpret_cast<const float4*>(props + (size_t)row * 4);
    float w  = __fsub_rn(p.z, p.x);
    float h  = __fsub_rn(p.w, p.y);
    float cx = __fadd_rn(p.x, __fmul_rn(0.5f, w));
    float cy = __fadd_rn(p.y, __fmul_rn(0.5f, h));

    const float4 r4 = *reinterpret_cast<const float4*>(
        reg + (size_t)row * (NC * 4) + (size_t)c * 4);
    float dx = __fdiv_rn(r4.x, 10.0f);
    float dy = __fdiv_rn(r4.y, 10.0f);
    float dw = fminf(__fdiv_rn(r4.z, 5.0f), BBOX_CLIP);
    float dh = fminf(__fdiv_rn(r4.w, 5.0f), BBOX_CLIP);

    float pcx = __fadd_rn(__fmul_rn(dx, w), cx);
    float pcy = __fadd_rn(__fmul_rn(dy, h), cy);
    float pw  = __fmul_rn(expf(dw), w);
    float ph  = __fmul_rn(expf(dh), h);

    float x1 = __fsub_rn(pcx, __fmul_rn(0.5f, pw));
    float y1 = __fsub_rn(pcy, __fmul_rn(0.5f, ph));
    float x2 = __fadd_rn(pcx, __fmul_rn(0.5f, pw));
    float y2 = __fadd_rn(pcy, __fmul_rn(0.5f, ph));
    x1 = fminf(fmaxf(x1, 0.0f), 800.0f);
    y1 = fminf(fmaxf(y1, 0.0f), 800.0f);
    x2 = fminf(fmaxf(x2, 0.0f), 800.0f);
    y2 = fminf(fmaxf(y2, 0.0f), 800.0f);

    out[0] = score; out[1] = x1; out[2] = y1; out[3] = x2; out[4] = y2;
    float ws_ = __fsub_rn(x2, x1);
    float hs_ = __fsub_rn(y2, y1);
    return (score > SCORE_TH) && (ws_ >= MIN_SIZE) && (hs_ >= MIN_SIZE);
}

// ---- fused: stats + prefilter + slot-deterministic fill (bitmask) | matcher
// entry record (8 floats, 32B): x1,y1,x2,y2,score,id,pad,pad @ slot = nprop
__global__ __launch_bounds__(256) void fused_kernel(
    const float* __restrict__ logits, const float* __restrict__ reg,
    const float* __restrict__ props, const float* __restrict__ gtb,
    const int* __restrict__ gtl,
    float* __restrict__ out_assigned, float* __restrict__ out_matched,
    unsigned long long* __restrict__ masks, float* __restrict__ ent)
{
    int bid = blockIdx.x;
    if (bid < RS_BLOCKS) {
        int wid = threadIdx.x >> 6, lane = threadIdx.x & 63;
        int row = bid * 4 + wid;                 // [0, 24000)
        const float* rp = logits + (size_t)row * NC;
        float l0 = rp[lane];
        float l1 = (lane < NC - 64) ? rp[64 + lane] : -INFINITY;
        float m = fmaxf(fmaxf(-INFINITY, l0), l1);
        for (int o = 32; o; o >>= 1) m = fmaxf(m, __shfl_down(m, o));
        m = __shfl(m, 0);
        float s = __fadd_rn(__fadd_rn(0.0f, expf(__fsub_rn(l0, m))),
                            expf(__fsub_rn(l1, m)));   // exp(-inf)=0 exact
        for (int o = 32; o; o >>= 1) s = __fadd_rn(s, __shfl_down(s, o));
        float s0 = __shfl(s, 0);
        // conservative prefilter: score>0.05 => l > m + log(0.04*s)
        float thr = __fadd_rn(m, logf(__fmul_rn(0.04f, s0)));

        int b = row / NN;
        int nprop = row - b * NN;

        if (lane >= 1 && l0 > thr) {
            float o[5];
            if (decode_one(reg, props, l0, m, s0, row, lane, o)) {
                int g = b * NCLS + (lane - 1);
                float* e = ent + ((size_t)g * NN + nprop) * 8;
                *reinterpret_cast<float4*>(e) =
                    make_float4(o[1], o[2], o[3], o[4]);
                *reinterpret_cast<float2*>(e + 4) =
                    make_float2(o[0], (float)(nprop * NCLS + (lane - 1)));
                atomicOr(&masks[(size_t)g * NWRD_P + (nprop >> 6)],
                         1ull << (nprop & 63));   // fire-and-forget
            }
        }
        if (lane < NC - 64 && l1 > thr) {
            float o[5];
            int c = lane + 64;
            if (decode_one(reg, props, l1, m, s0, row, c, o)) {
                int g = b * NCLS + (c - 1);
                float* e = ent + ((size_t)g * NN + nprop) * 8;
                *reinterpret_cast<float4*>(e) =
                    make_float4(o[1], o[2], o[3], o[4]);
                *reinterpret_cast<float2*>(e + 4) =
                    make_float2(o[0], (float)(nprop * NCLS + (c - 1)));
                atomicOr(&masks[(size_t)g * NWRD_P + (nprop >> 6)],
                         1ull << (nprop & 63));   // fire-and-forget
            }
        }
    } else {
        // ---- matcher blocks ----
        int t = (bid - RS_BLOCKS) * 256 + threadIdx.x;
        if (t >= NB * NN) return;
        int b = t / NN;
        const float4 p = *reinterpret_cast<const float4*>(props + (size_t)t * 4);
        float parea = __fmul_rn(__fsub_rn(p.z, p.x), __fsub_rn(p.w, p.y));
        float best = -1.0f; int bi = -1;
        for (int g = 0; g < NG; ++g) {
            const float4 q = *reinterpret_cast<const float4*>(gtb + ((size_t)b * NG + g) * 4);
            float garea = __fmul_rn(__fsub_rn(q.z, q.x), __fsub_rn(q.w, q.y));
            float ltx = fmaxf(q.x, p.x), lty = fmaxf(q.y, p.y);
            float rbx = fminf(q.z, p.z), rby = fminf(q.w, p.w);
            float wx = fmaxf(__fsub_rn(rbx, ltx), 0.0f);
            float wy = fmaxf(__fsub_rn(rby, lty), 0.0f);
            float inter = __fmul_rn(wx, wy);
            float iou = __fdiv_rn(inter, __fsub_rn(__fadd_rn(garea, parea), inter));
            if (iou > best) { best = iou; bi = g; }
        }
        int matched = (best >= MATCH_TH) ? bi : -1;
        int assigned = (matched >= 0) ? gtl[b * NG + matched] : 0;
        out_matched[t]  = (float)matched;
        out_assigned[t] = (float)assigned;
    }
}

// -------- sparse exact fallback for n_total > PMAX (never expected) --------
__device__ void nms_glb_sparse(int g, const unsigned long long* __restrict__ M,
                               float* __restrict__ E, float tb, float cls,
                               float* __restrict__ selbuf, int* __restrict__ selcnt)
{
    int lane = threadIdx.x & 63;
    int kout = 0;
    for (int k = 0; k < NK; ++k) {
        float bv = -INFINITY, boi = INFINITY; int bi = -1;
        for (int i = lane; i < NN; i += 64) {
            if (!((M[i >> 6] >> (i & 63)) & 1ull)) continue;
            float v = E[(size_t)i * 8 + 4], oi = E[(size_t)i * 8 + 5];
            if (v > bv || (v == bv && oi < boi)) { bv = v; boi = oi; bi = i; }
        }
        int wl = lane;
        for (int o = 1; o < 64; o <<= 1) {
            float v2 = __shfl_xor(bv, o); float o2 = __shfl_xor(boi, o);
            int l2 = __shfl_xor(wl, o);
            bool bt = (v2 > bv) || (v2 == bv && o2 < boi);
            bv = bt ? v2 : bv; boi = bt ? o2 : boi; wl = bt ? l2 : wl;
        }
        if (bv == -INFINITY) break;
        int wi = __shfl(bi, wl);
        float sx1 = E[(size_t)wi * 8 + 0], sy1 = E[(size_t)wi * 8 + 1];
        float sx2 = E[(size_t)wi * 8 + 2], sy2 = E[(size_t)wi * 8 + 3];
        if (lane == wl) {
            float* so = selbuf + ((size_t)g * NK + k) * 8;
            so[0] = bv; so[1] = sx1; so[2] = sy1; so[3] = sx2; so[4] = sy2;
            so[5] = cls; so[6] = boi; so[7] = 0.0f;
        }
        float bx1 = __fadd_rn(sx1, tb), by1 = __fadd_rn(sy1, tb);
        float bx2 = __fadd_rn(sx2, tb), by2 = __fadd_rn(sy2, tb);
        float sar = __fmul_rn(__fsub_rn(bx2, bx1), __fsub_rn(by2, by1));
        for (int i = lane; i < NN; i += 64) {
            if (!((M[i >> 6] >> (i & 63)) & 1ull)) continue;
            float v = E[(size_t)i * 8 + 4];
            if (v == -INFINITY) continue;
            float ox1 = __fadd_rn(E[(size_t)i * 8 + 0], tb);
            float oy1 = __fadd_rn(E[(size_t)i * 8 + 1], tb);
            float ox2 = __fadd_rn(E[(size_t)i * 8 + 2], tb);
            float oy2 = __fadd_rn(E[(size_t)i * 8 + 3], tb);
            float oar = __fmul_rn(__fsub_rn(ox2, ox1), __fsub_rn(oy2, oy1));
            float ltx = fmaxf(ox1, bx1), lty = fmaxf(oy1, by1);
            float rbx = fminf(ox2, bx2), rby = fminf(oy2, by2);
            float wx = fmaxf(__fsub_rn(rbx, ltx), 0.0f);
            float wy = fmaxf(__fsub_rn(rby, lty), 0.0f);
            float inter = __fmul_rn(wx, wy);
            float den = __fsub_rn(__fadd_rn(oar, sar), inter);
            if ((double)inter > C_SUP * (double)den) E[(size_t)i * 8 + 4] = -INFINITY;
        }
        kout = k + 1;
    }
    if (lane == 0) selcnt[g] = kout;
}

template <int CAP>
__device__ __forceinline__ float selN(const float a[CAP], int j) {
    float r = a[0];
#pragma unroll
    for (int i = 1; i < CAP; ++i) r = (j == i) ? a[i] : r;
    return r;
}
__device__ __forceinline__ float rdlane(float v, int l) {
    return __uint_as_float(
        (unsigned)__builtin_amdgcn_readlane((int)__float_as_uint(v), l));
}
__device__ __forceinline__ unsigned long long rdlane64(unsigned long long v, int l) {
    unsigned lo = (unsigned)__builtin_amdgcn_readlane((int)(unsigned)v, l);
    unsigned hi = (unsigned)__builtin_amdgcn_readlane((int)(unsigned)(v >> 32), l);
    return ((unsigned long long)hi << 32) | lo;
}

// exact register sweep (fallback; identical semantics to round-10 main path)
template <int CAP>
__device__ __forceinline__ int sweep_reg(
    int lane, int n, float tb,
    const float* sx1, const float* sy1, const float* sx2, const float* sy2,
    int* acc)
{
    float ox1[CAP], oy1[CAP], ox2[CAP], oy2[CAP], oar[CAP];
    unsigned alive = 0;
#pragma unroll
    for (int j = 0; j < CAP; ++j) {
        int sidx = lane * CAP + j;
        if (sidx < n) {
            float a  = __fadd_rn(sx1[sidx], tb);
            float b_ = __fadd_rn(sy1[sidx], tb);
            float c_ = __fadd_rn(sx2[sidx], tb);
            float d_ = __fadd_rn(sy2[sidx], tb);
            ox1[j] = a; oy1[j] = b_; ox2[j] = c_; oy2[j] = d_;
            oar[j] = __fmul_rn(__fsub_rn(c_, a), __fsub_rn(d_, b_));
            alive |= 1u << j;
        } else {
            ox1[j] = 0.f; oy1[j] = 0.f; ox2[j] = 0.f; oy2[j] = 0.f; oar[j] = 0.f;
        }
    }
    int kout = 0;
    while (kout < NK) {
        unsigned long long bal = __ballot(alive != 0u);
        if (!bal) break;
        int fl = (int)__ffsll(bal) - 1;                           // uniform
        unsigned am = (unsigned)__builtin_amdgcn_readlane((int)alive, fl);
        int js = __ffs(am) - 1;                                   // uniform
        float bx1 = rdlane(selN<CAP>(ox1, js), fl);
        float by1 = rdlane(selN<CAP>(oy1, js), fl);
        float bx2 = rdlane(selN<CAP>(ox2, js), fl);
        float by2 = rdlane(selN<CAP>(oy2, js), fl);
        float bar = rdlane(selN<CAP>(oar, js), fl);
        if (lane == 0) acc[kout] = fl * CAP + js;
        kout++;
        unsigned kill = 0;
#pragma unroll
        for (int j = 0; j < CAP; ++j) {
            float ltx = fmaxf(ox1[j], bx1), lty = fmaxf(oy1[j], by1);
            float rbx = fminf(ox2[j], bx2), rby = fminf(oy2[j], by2);
            float wx = fmaxf(__fsub_rn(rbx, ltx), 0.0f);
            float wy = fmaxf(__fsub_rn(rby, lty), 0.0f);
            float inter = __fmul_rn(wx, wy);
            float den = __fsub_rn(__fadd_rn(oar[j], bar), inter);
            if ((double)inter > C_SUP * (double)den) kill |= 1u << j;
        }
        alive &= ~kill;
    }
    return kout;
}

// -- 512-thr: bitmask compaction + sort + ballot matrix + scalar sweep ------
__global__ __launch_bounds__(512) void bucket_nms_kernel(
    const unsigned long long* __restrict__ masks,
    float* __restrict__ entries,
    float* __restrict__ selbuf, int* __restrict__ selcnt)
{
    int g = blockIdx.x;
    int tid = threadIdx.x;
    float* E = entries + (size_t)g * NN * 8;
    const unsigned long long* M = masks + (size_t)g * NWRD_P;
    float cls = (float)(g % NCLS + 1);
    float tb = __fmul_rn(cls, 801.0f);

    __shared__ int sidx[PMAX];
    __shared__ int woff[NWRD + 1];
    __shared__ unsigned skhi[PMAX], sklo[PMAX];
    __shared__ int sperm[PMAX];
    __shared__ float sx1[PMAX], sy1[PMAX], sx2[PMAX], sy2[PMAX];
    __shared__ unsigned long long dmask[MATW * 4];   // 8 KB
    __shared__ int acc[NK];
    __shared__ int s_kout, s_fb;

    // phase 0: bitmask -> deterministic compaction (ascending slot order)
    unsigned long long myw = (tid < NWRD) ? M[tid] : 0ull;
    if (tid < NWRD) woff[tid] = __popcll(myw);
    __syncthreads();
    if (tid == 0) {
        int a = 0;
        for (int w = 0; w < NWRD; ++w) { int c = woff[w]; woff[w] = a; a += c; }
        woff[NWRD] = a;
    }
    __syncthreads();
    int n = woff[NWRD];
    if (n == 0) { if (tid == 0) selcnt[g] = 0; return; }
    if (n > PMAX) {   // never expected; exact sparse path
        if (tid < 64) nms_glb_sparse(g, M, E, tb, cls, selbuf, selcnt);
        return;
    }
    if (tid < NWRD) {
        unsigned long long m = myw;
        int base = woff[tid], r = 0;
        while (m) {
            int b = (int)__ffsll(m) - 1;
            sidx[base + r] = tid * 64 + b;
            r++; m &= m - 1;
        }
    }
    __syncthreads();

    int P = 64; while (P < n) P <<= 1;

    for (int i = tid; i < P; i += 512) {
        if (i < n) {
            const float2 kv = *reinterpret_cast<const float2*>(
                E + (size_t)sidx[i] * 8 + 4);
            skhi[i] = __float_as_uint(kv.x);
            sklo[i] = ~((unsigned)kv.y);   // u64 max == (score desc, idx asc)
        } else { skhi[i] = 0u; sklo[i] = 0u; }
        sperm[i] = i;
    }
    __syncthreads();
    // bitonic sort desc; j<128 stages wave-local
    for (int k = 2; k <= P; k <<= 1) {
        for (int j = k >> 1; j > 0; j >>= 1) {
            bool cross = (j >= 128);
            if (cross) __syncthreads();
            for (int t = tid; t < (P >> 1); t += 512) {
                int i = ((t & ~(j - 1)) << 1) | (t & (j - 1));
                int l = i | j;
                unsigned ah = skhi[i], al = sklo[i], ch = skhi[l], cl_ = sklo[l];
                bool alt = (ah < ch) || (ah == ch && al < cl_);
                bool agt = (ah > ch) || (ah == ch && al > cl_);
                bool sw = ((i & k) == 0) ? alt : agt;
                if (sw) {
                    skhi[i] = ch; sklo[i] = cl_; skhi[l] = ah; sklo[l] = al;
                    int tp = sperm[i]; sperm[i] = sperm[l]; sperm[l] = tp;
                }
            }
            if (cross) __syncthreads();
            else CFENCE();
        }
    }
    __syncthreads();
    // stage RAW coords in sorted order (one 16B load per entry)
    for (int i = tid; i < n; i += 512) {
        const float4 v = *reinterpret_cast<const float4*>(
            E + (size_t)sidx[sperm[i]] * 8);
        sx1[i] = v.x; sy1[i] = v.y; sx2[i] = v.z; sy2[i] = v.w;
    }
    __syncthreads();

    int W = (n < MATW) ? n : MATW;
    int nchunk = (W + 63) >> 6;
    int wv = tid >> 6, lane = tid & 63;

    // j-chunk boxes (offset coords) in registers
    float jx1[4], jy1[4], jx2[4], jy2[4], jar[4];
#pragma unroll
    for (int c = 0; c < 4; ++c) {
        int j = c * 64 + lane;
        if (j < W) {
            float a  = __fadd_rn(sx1[j], tb);
            float b_ = __fadd_rn(sy1[j], tb);
            float c_ = __fadd_rn(sx2[j], tb);
            float d_ = __fadd_rn(sy2[j], tb);
            jx1[c] = a; jy1[c] = b_; jx2[c] = c_; jy2[c] = d_;
            jar[c] = __fmul_rn(__fsub_rn(c_, a), __fsub_rn(d_, b_));
        } else {
            jx1[c] = 0.f; jy1[c] = 0.f; jx2[c] = 0.f; jy2[c] = 0.f; jar[c] = 0.f;
        }
    }
    // matrix rows striped across 8 waves; uniform LDS row read + prefetch
    {
        int i0 = wv;
        float nx1 = 0.f, ny1 = 0.f, nx2 = 0.f, ny2 = 0.f;
        if (i0 < W) { nx1 = sx1[i0]; ny1 = sy1[i0]; nx2 = sx2[i0]; ny2 = sy2[i0]; }
        for (int i = i0; i < W; i += 8) {
            float rx1 = nx1, ry1 = ny1, rx2 = nx2, ry2 = ny2;
            int ni = i + 8;
            if (ni < W) { nx1 = sx1[ni]; ny1 = sy1[ni]; nx2 = sx2[ni]; ny2 = sy2[ni]; }
            float bx1 = __fadd_rn(rx1, tb), by1 = __fadd_rn(ry1, tb);
            float bx2 = __fadd_rn(rx2, tb), by2 = __fadd_rn(ry2, tb);
            float bar = __fmul_rn(__fsub_rn(bx2, bx1), __fsub_rn(by2, by1));
            int ic = i >> 6;
#pragma unroll
            for (int c = 0; c < 4; ++c) {
                if (c >= ic && c < nchunk) {
                    bool jv = (c * 64 + lane) < W;
                    float ltx = fmaxf(jx1[c], bx1), lty = fmaxf(jy1[c], by1);
                    float rbx = fminf(jx2[c], bx2), rby = fminf(jy2[c], by2);
                    float wx = fmaxf(__fsub_rn(rbx, ltx), 0.0f);
                    float wy = fmaxf(__fsub_rn(rby, lty), 0.0f);
                    float inter = __fmul_rn(wx, wy);
                    float den = __fsub_rn(__fadd_rn(jar[c], bar), inter);
                    bool sup = jv && ((double)inter > C_SUP * (double)den);
                    unsigned long long w64 = __ballot(sup);
                    if (lane == 0) dmask[i * 4 + c] = w64;
                }
            }
        }
    }
    __syncthreads();

    // SCALAR bit sweep on wave 0 (wave-uniform alive words)
    if (tid < 64) {
        unsigned long long a0 = 0, a1 = 0, a2 = 0, a3 = 0;
        {
            int rem = W;
            a0 = (rem >= 64) ? ~0ull : ((rem > 0) ? ((1ull << rem) - 1) : 0); rem -= 64;
            a1 = (rem >= 64) ? ~0ull : ((rem > 0) ? ((1ull << rem) - 1) : 0); rem -= 64;
            a2 = (rem >= 64) ? ~0ull : ((rem > 0) ? ((1ull << rem) - 1) : 0); rem -= 64;
            a3 = (rem >= 64) ? ~0ull : ((rem > 0) ? ((1ull << rem) - 1) : 0);
        }
        int kout = 0;
        while (kout < NK) {
            int cand;
            if      (a0) cand = (int)__ffsll(a0) - 1;
            else if (a1) cand = 64  + (int)__ffsll(a1) - 1;
            else if (a2) cand = 128 + (int)__ffsll(a2) - 1;
            else if (a3) cand = 192 + (int)__ffsll(a3) - 1;
            else break;
            if (lane == 0) acc[kout] = cand;
            kout++;
            unsigned long long mrow = (lane < 4) ? dmask[cand * 4 + lane] : 0ull;
            a0 &= ~rdlane64(mrow, 0);
            a1 &= ~rdlane64(mrow, 1);
            a2 &= ~rdlane64(mrow, 2);
            a3 &= ~rdlane64(mrow, 3);
        }
        if (lane == 0) {
            s_kout = kout;
            s_fb = (kout < NK && n > W) ? 1 : 0;   // prefix exhausted early
        }
    }
    __syncthreads();

    if (s_fb) {
        // exact fallback (rare): redo from scratch with the register sweep
        if (tid < 64) {
            int kout = sweep_reg<8>(lane, n, tb, sx1, sy1, sx2, sy2, acc);
            if (lane == 0) s_kout = kout;
        }
        __syncthreads();
    }

    int kc = s_kout;
    if (tid == 0) selcnt[g] = kc;
    for (int k = tid; k < kc; k += 512) {
        int cand = acc[k];
        float* so = selbuf + ((size_t)g * NK + k) * 8;
        so[0] = __uint_as_float(skhi[cand]);
        so[1] = sx1[cand]; so[2] = sy1[cand];
        so[3] = sx2[cand]; so[4] = sy2[cand];
        so[5] = cls; so[6] = (float)(~sklo[cand]); so[7] = 0.0f;
    }
}

// ------ merge: exact parallel top-K via LB bound (unchanged from r13) ------
__global__ __launch_bounds__(512) void merge_kernel(
    const float* __restrict__ selbuf, const int* __restrict__ selcnt,
    float* __restrict__ out_dets, float* __restrict__ out_kl)
{
    int b = blockIdx.x, tid = threadIdx.x;
    __shared__ int scnt[NCLS], soff[NCLS + 1];
    __shared__ unsigned akhi[512], aklo[512];
    __shared__ unsigned bkhi[MPB], bklo[MPB], bpay[MPB];
    __shared__ int s_T, s_cntA;
    __shared__ unsigned s_LBhi, s_LBlo;

    if (tid < NCLS) scnt[tid] = selcnt[b * NCLS + tid];
    if (tid == 0) s_T = 0;
    __syncthreads();
    if (tid == 0) {
        int a = 0, ca = 0;
        for (int c = 0; c < NCLS; ++c) {
            soff[c] = a; a += scnt[c];
            ca += (scnt[c] < 4 ? scnt[c] : 4);
        }
        soff[NCLS] = a; s_cntA = ca;
    }
    __syncthreads();
    int tot = soff[NCLS];

    if (tot == 0) {
        for (int z = tid; z < NK * 5; z += 512) out_dets[(size_t)b * NK * 5 + z] = 0.0f;
        for (int z = tid; z < NK; z += 512)     out_kl[(size_t)b * NK + z] = -1.0f;
        return;
    }

    {
        unsigned kh = 0u, kl = 0u;
        if (tid < NCLS * 4) {
            int c = tid >> 2, i = tid & 3;
            if (i < scnt[c]) {
                const float* e = selbuf + ((size_t)(b * NCLS + c) * NK + i) * 8;
                kh = __float_as_uint(e[0]); kl = ~((unsigned)e[6]);
            }
        }
        akhi[tid] = kh; aklo[tid] = kl;
    }
    __syncthreads();
    for (int k = 2; k <= 512; k <<= 1) {
        for (int j = k >> 1; j > 0; j >>= 1) {
            bool cross = (j >= 128);
            if (cross) __syncthreads();
            if (tid < 256) {
                int t = tid;
                int i = ((t & ~(j - 1)) << 1) | (t & (j - 1));
                int l = i | j;
                unsigned ah = akhi[i], al = aklo[i], ch = akhi[l], cl_ = aklo[l];
                bool alt = (ah < ch) || (ah == ch && al < cl_);
                bool agt = (ah > ch) || (ah == ch && al > cl_);
                bool sw = ((i & k) == 0) ? alt : agt;
                if (sw) {
                    akhi[i] = ch; aklo[i] = cl_; akhi[l] = ah; aklo[l] = al;
                }
            }
            if (cross) __syncthreads();
            else CFENCE();
        }
    }
    __syncthreads();
    if (tid == 0) {
        if (s_cntA >= NK) { s_LBhi = akhi[NK - 1]; s_LBlo = aklo[NK - 1]; }
        else              { s_LBhi = 0u;           s_LBlo = 0u; }
    }
    __syncthreads();
    unsigned LBhi = s_LBhi, LBlo = s_LBlo;

    for (int flat = tid; flat < tot; flat += 512) {
        int lo = 0, hi = NCLS - 1;
        while (lo < hi) { int mid = (lo + hi + 1) >> 1;
                          if (soff[mid] <= flat) lo = mid; else hi = mid - 1; }
        int c = lo, i = flat - soff[c];
        const float* e = selbuf + ((size_t)(b * NCLS + c) * NK + i) * 8;
        unsigned kh = __float_as_uint(e[0]), kl = ~((unsigned)e[6]);
        bool ge = (kh > LBhi) || (kh == LBhi && kl >= LBlo);
        if (ge) {
            int pos = atomicAdd(&s_T, 1);
            if (pos < MPB) { bkhi[pos] = kh; bklo[pos] = kl;
                             bpay[pos] = (unsigned)((c << 7) | i); }
        }
    }
    __syncthreads();
    int T = s_T;

    if (T > MPB) {
        if (tid >= 64) return;
        int lane = tid;
        int g0 = b * NCLS + lane;
        int g1 = (lane < NCLS - 64) ? g0 + 64 : -1;
        int c0 = scnt[lane];
        int c1 = (g1 >= 0) ? scnt[lane + 64] : 0;
        int p0 = 0, p1 = 0;
        unsigned long long k0c = 0, k1c = 0;
        if (p0 < c0) { const float* h = selbuf + ((size_t)g0 * NK) * 8;
            k0c = ((unsigned long long)__float_as_uint(h[0]) << 32) | (unsigned long long)(~(unsigned)h[6]); }
        if (g1 >= 0 && p1 < c1) { const float* h = selbuf + ((size_t)g1 * NK) * 8;
            k1c = ((unsigned long long)__float_as_uint(h[0]) << 32) | (unsigned long long)(~(unsigned)h[6]); }
        for (int k = 0; k < NK; ++k) {
            bool t1 = (k1c > k0c);
            unsigned long long bk = t1 ? k1c : k0c;
            int bslot = t1 ? (lane + 64) : lane;
            for (int o = 1; o < 64; o <<= 1) {
                unsigned long long k2 = __shfl_xor(bk, o);
                int b2 = __shfl_xor(bslot, o);
                if (k2 > bk) { bk = k2; bslot = b2; }
            }
            if (bk == 0ull) {
                for (int z = k * 5 + lane; z < NK * 5; z += 64)
                    out_dets[(size_t)b * NK * 5 + z] = 0.0f;
                for (int z = k + lane; z < NK; z += 64)
                    out_kl[(size_t)b * NK + z] = -1.0f;
                return;
            }
            int owner = bslot & 63;
            if (lane == owner) {
                bool isA = (bslot < 64);
                int gg = isA ? g0 : g1;
                int pp = isA ? p0 : p1;
                const float* e = selbuf + ((size_t)gg * NK + pp) * 8;
                size_t o = ((size_t)b * NK + k) * 5;
                out_dets[o + 0] = e[1]; out_dets[o + 1] = e[2];
                out_dets[o + 2] = e[3]; out_dets[o + 3] = e[4];
                out_dets[o + 4] = e[0];
                out_kl[(size_t)b * NK + k] = e[5];
                if (isA) {
                    p0++; k0c = 0;
                    if (p0 < c0) { const float* h = selbuf + ((size_t)g0 * NK + p0) * 8;
                        k0c = ((unsigned long long)__float_as_uint(h[0]) << 32) | (unsigned long long)(~(unsigned)h[6]); }
                } else {
                    p1++; k1c = 0;
                    if (p1 < c1) { const float* h = selbuf + ((size_t)g1 * NK + p1) * 8;
                        k1c = ((unsigned long long)__float_as_uint(h[0]) << 32) | (unsigned long long)(~(unsigned)h[6]); }
                }
            }
        }
        return;
    }

    int P = 128; while (P < T) P <<= 1;
    for (int i = T + tid; i < P; i += 512) { bkhi[i] = 0u; bklo[i] = 0u; bpay[i] = 0u; }
    __syncthreads();
    for (int k = 2; k <= P; k <<= 1) {
        for (int j = k >> 1; j > 0; j >>= 1) {
            bool cross = (j >= 128);
            if (cross) __syncthreads();
            for (int t = tid; t < (P >> 1); t += 512) {
                int i = ((t & ~(j - 1)) << 1) | (t & (j - 1));
                int l = i | j;
                unsigned ah = bkhi[i], al = bklo[i], ch = bkhi[l], cl_ = bklo[l];
                bool alt = (ah < ch) || (ah == ch && al < cl_);
                bool agt = (ah > ch) || (ah == ch && al > cl_);
                bool sw = ((i & k) == 0) ? alt : agt;
                if (sw) {
                    bkhi[i] = ch; bklo[i] = cl_; bkhi[l] = ah; bklo[l] = al;
                    unsigned tp = bpay[i]; bpay[i] = bpay[l]; bpay[l] = tp;
                }
            }
            if (cross) __syncthreads();
            else CFENCE();
        }
    }
    __syncthreads();
    int kc = (T < NK) ? T : NK;
    for (int k = tid; k < NK; k += 512) {
        size_t o = ((size_t)b * NK + k) * 5;
        if (k < kc) {
            unsigned pay = bpay[k];
            int c = (int)(pay >> 7), p = (int)(pay & 127);
            const float* e = selbuf + ((size_t)(b * NCLS + c) * NK + p) * 8;
            out_dets[o + 0] = e[1]; out_dets[o + 1] = e[2];
            out_dets[o + 2] = e[3]; out_dets[o + 3] = e[4];
            out_dets[o + 4] = e[0];
            out_kl[(size_t)b * NK + k] = e[5];
        } else {
            out_dets[o + 0] = 0.0f; out_dets[o + 1] = 0.0f;
            out_dets[o + 2] = 0.0f; out_dets[o + 3] = 0.0f;
            out_dets[o + 4] = 0.0f;
            out_kl[(size_t)b * NK + k] = -1.0f;
        }
    }
}

extern "C" void kernel_launch(void* const* d_in, const int* in_sizes, int n_in,
                              void* d_out, int out_size, void* d_ws, size_t ws_size,
                              hipStream_t stream) {
    const float* logits = (const float*)d_in[0];
    const float* reg    = (const float*)d_in[1];
    const float* props  = (const float*)d_in[2];
    const float* gtb    = (const float*)d_in[3];
    const int*   gtl    = (const int*)d_in[4];

    float* out          = (float*)d_out;
    float* out_dets     = out;                    // NB*NK*5 = 2000
    float* out_kl       = out + NB * NK * 5;      // NB*NK   = 400
    float* out_assigned = out_kl + NB * NK;       // NB*NN   = 24000
    float* out_matched  = out_assigned + NB * NN; // NB*NN   = 24000

    char* ws = (char*)d_ws;
    int*   selcnt  = (int*)(ws + 0);                        // 1440 B
    float* selbuf  = (float*)(ws + 65536);                  // 1152000 B
    unsigned long long* masks =
        (unsigned long long*)(ws + 2097152);                // 360*96*8 = 276480 B
    float* entries = (float*)(ws + 8388608);                // 360*6000*32B = 69.1 MB

    hipMemsetAsync(masks, 0, (size_t)NBUC * NWRD_P * sizeof(unsigned long long),
                   stream);
    const int MATCH_BLOCKS = (NB * NN + 255) / 256;   // 94
    fused_kernel<<<RS_BLOCKS + MATCH_BLOCKS, 256, 0, stream>>>(
        logits, reg, props, gtb, gtl, out_assigned, out_matched,
        masks, entries);
    bucket_nms_kernel<<<NBUC, 512, 0, stream>>>(
        masks, entries, selbuf, selcnt);
    merge_kernel<<<NB, 512, 0, stream>>>(selbuf, selcnt, out_dets, out_kl);
}

// Round 20
// 115.270 us; speedup vs baseline: 1.0347x; 1.0043x over previous
//
#include <hip/hip_runtime.h>
#include <math.h>

#define NB 4
#define NN 6000
#define NC 91
#define NG 32
#define NK 100
#define NCLS (NC - 1)        /* 90 */
#define NBUC (NB * NCLS)     /* 360 */
#define NWRD 94              /* ceil(NN/64) validity-mask words per bucket */
#define NWRD_P 96            /* padded stride */
#define PMAX 512             /* fast-path bucket capacity */
#define MATW 256             /* suppression-matrix prefix width */
#define MPB 4096             /* merge stage-B capacity per image */
#define RS_BLOCKS 6000       /* 24000 rows / 4 waves per block */

#define SCORE_TH 0.05f
#define NMS_TH 0.5f
#define MATCH_TH 0.5f
#define MIN_SIZE 0.01f
#define BBOX_CLIP 4.135166556742356f  /* log(1000/16) */
/* fdiv_rn(inter,den) > 0.5f  <=>  (double)inter > C_SUP*(double)den  (exact) */
#define C_SUP 0.5000000298023223876953125

#define CFENCE() asm volatile("" ::: "memory")

// ---------------- decode (identical op sequence to rounds 1-18) ------------
__device__ __forceinline__ bool decode_one(
    const float* __restrict__ reg, const float* __restrict__ props,
    float l, float m, float s0, int row, int c, float out[5])
{
    float score = __fdiv_rn(expf(__fsub_rn(l, m)), s0);

    const float4 p = *reinterpret_cast<const float4*>(props + (size_t)row * 4);
    float w  = __fsub_rn(p.z, p.x);
    float h  = __fsub_rn(p.w, p.y);
    float cx = __fadd_rn(p.x, __fmul_rn(0.5f, w));
    float cy = __fadd_rn(p.y, __fmul_rn(0.5f, h));

    const float4 r4 = *reinterpret_cast<const float4*>(
        reg + (size_t)row * (NC * 4) + (size_t)c * 4);
    float dx = __fdiv_rn(r4.x, 10.0f);
    float dy = __fdiv_rn(r4.y, 10.0f);
    float dw = fminf(__fdiv_rn(r4.z, 5.0f), BBOX_CLIP);
    float dh = fminf(__fdiv_rn(r4.w, 5.0f), BBOX_CLIP);

    float pcx = __fadd_rn(__fmul_rn(dx, w), cx);
    float pcy = __fadd_rn(__fmul_rn(dy, h), cy);
    float pw  = __fmul_rn(expf(dw), w);
    float ph  = __fmul_rn(expf(dh), h);

    float x1 = __fsub_rn(pcx, __fmul_rn(0.5f, pw));
    float y1 = __fsub_rn(pcy, __fmul_rn(0.5f, ph));
    float x2 = __fadd_rn(pcx, __fmul_rn(0.5f, pw));
    float y2 = __fadd_rn(pcy, __fmul_rn(0.5f, ph));
    x1 = fminf(fmaxf(x1, 0.0f), 800.0f);
    y1 = fminf(fmaxf(y1, 0.0f), 800.0f);
    x2 = fminf(fmaxf(x2, 0.0f), 800.0f);
    y2 = fminf(fmaxf(y2, 0.0f), 800.0f);

    out[0] = score; out[1] = x1; out[2] = y1; out[3] = x2; out[4] = y2;
    float ws_ = __fsub_rn(x2, x1);
    float hs_ = __fsub_rn(y2, y1);
    return (score > SCORE_TH) && (ws_ >= MIN_SIZE) && (hs_ >= MIN_SIZE);
}

// ---- fused: stats + prefilter + slot-deterministic fill (bitmask) | matcher
// entry record (8 floats, 32B): x1,y1,x2,y2,score,id,pad,pad @ slot = nprop
__global__ __launch_bounds__(256) void fused_kernel(
    const float* __restrict__ logits, const float* __restrict__ reg,
    const float* __restrict__ props, const float* __restrict__ gtb,
    const int* __restrict__ gtl,
    float* __restrict__ out_assigned, float* __restrict__ out_matched,
    unsigned long long* __restrict__ masks, float* __restrict__ ent)
{
    int bid = blockIdx.x;
    if (bid < RS_BLOCKS) {
        int wid = threadIdx.x >> 6, lane = threadIdx.x & 63;
        int row = bid * 4 + wid;                 // [0, 24000)
        const float* rp = logits + (size_t)row * NC;
        float l0 = rp[lane];
        float l1 = (lane < NC - 64) ? rp[64 + lane] : -INFINITY;
        float m = fmaxf(fmaxf(-INFINITY, l0), l1);
        for (int o = 32; o; o >>= 1) m = fmaxf(m, __shfl_down(m, o));
        m = __shfl(m, 0);
        float s = __fadd_rn(__fadd_rn(0.0f, expf(__fsub_rn(l0, m))),
                            expf(__fsub_rn(l1, m)));   // exp(-inf)=0 exact
        for (int o = 32; o; o >>= 1) s = __fadd_rn(s, __shfl_down(s, o));
        float s0 = __shfl(s, 0);
        // conservative prefilter: score>0.05 => l > m + log(0.04*s)
        float thr = __fadd_rn(m, logf(__fmul_rn(0.04f, s0)));

        int b = row / NN;
        int nprop = row - b * NN;

        if (lane >= 1 && l0 > thr) {
            float o[5];
            if (decode_one(reg, props, l0, m, s0, row, lane, o)) {
                int g = b * NCLS + (lane - 1);
                float* e = ent + ((size_t)g * NN + nprop) * 8;
                *reinterpret_cast<float4*>(e) =
                    make_float4(o[1], o[2], o[3], o[4]);
                *reinterpret_cast<float2*>(e + 4) =
                    make_float2(o[0], (float)(nprop * NCLS + (lane - 1)));
                atomicOr(&masks[(size_t)g * NWRD_P + (nprop >> 6)],
                         1ull << (nprop & 63));   // fire-and-forget
            }
        }
        if (lane < NC - 64 && l1 > thr) {
            float o[5];
            int c = lane + 64;
            if (decode_one(reg, props, l1, m, s0, row, c, o)) {
                int g = b * NCLS + (c - 1);
                float* e = ent + ((size_t)g * NN + nprop) * 8;
                *reinterpret_cast<float4*>(e) =
                    make_float4(o[1], o[2], o[3], o[4]);
                *reinterpret_cast<float2*>(e + 4) =
                    make_float2(o[0], (float)(nprop * NCLS + (c - 1)));
                atomicOr(&masks[(size_t)g * NWRD_P + (nprop >> 6)],
                         1ull << (nprop & 63));   // fire-and-forget
            }
        }
    } else {
        // ---- matcher blocks ----
        int t = (bid - RS_BLOCKS) * 256 + threadIdx.x;
        if (t >= NB * NN) return;
        int b = t / NN;
        const float4 p = *reinterpret_cast<const float4*>(props + (size_t)t * 4);
        float parea = __fmul_rn(__fsub_rn(p.z, p.x), __fsub_rn(p.w, p.y));
        float best = -1.0f; int bi = -1;
        for (int g = 0; g < NG; ++g) {
            const float4 q = *reinterpret_cast<const float4*>(gtb + ((size_t)b * NG + g) * 4);
            float garea = __fmul_rn(__fsub_rn(q.z, q.x), __fsub_rn(q.w, q.y));
            float ltx = fmaxf(q.x, p.x), lty = fmaxf(q.y, p.y);
            float rbx = fminf(q.z, p.z), rby = fminf(q.w, p.w);
            float wx = fmaxf(__fsub_rn(rbx, ltx), 0.0f);
            float wy = fmaxf(__fsub_rn(rby, lty), 0.0f);
            float inter = __fmul_rn(wx, wy);
            float iou = __fdiv_rn(inter, __fsub_rn(__fadd_rn(garea, parea), inter));
            if (iou > best) { best = iou; bi = g; }
        }
        int matched = (best >= MATCH_TH) ? bi : -1;
        int assigned = (matched >= 0) ? gtl[b * NG + matched] : 0;
        out_matched[t]  = (float)matched;
        out_assigned[t] = (float)assigned;
    }
}

// -------- sparse exact fallback for n_total > PMAX (never expected) --------
__device__ void nms_glb_sparse(int g, const unsigned long long* __restrict__ M,
                               float* __restrict__ E, float tb, float cls,
                               float* __restrict__ selbuf, int* __restrict__ selcnt)
{
    int lane = threadIdx.x & 63;
    int kout = 0;
    for (int k = 0; k < NK; ++k) {
        float bv = -INFINITY, boi = INFINITY; int bi = -1;
        for (int i = lane; i < NN; i += 64) {
            if (!((M[i >> 6] >> (i & 63)) & 1ull)) continue;
            float v = E[(size_t)i * 8 + 4], oi = E[(size_t)i * 8 + 5];
            if (v > bv || (v == bv && oi < boi)) { bv = v; boi = oi; bi = i; }
        }
        int wl = lane;
        for (int o = 1; o < 64; o <<= 1) {
            float v2 = __shfl_xor(bv, o); float o2 = __shfl_xor(boi, o);
            int l2 = __shfl_xor(wl, o);
            bool bt = (v2 > bv) || (v2 == bv && o2 < boi);
            bv = bt ? v2 : bv; boi = bt ? o2 : boi; wl = bt ? l2 : wl;
        }
        if (bv == -INFINITY) break;
        int wi = __shfl(bi, wl);
        float sx1 = E[(size_t)wi * 8 + 0], sy1 = E[(size_t)wi * 8 + 1];
        float sx2 = E[(size_t)wi * 8 + 2], sy2 = E[(size_t)wi * 8 + 3];
        if (lane == wl) {
            float* so = selbuf + ((size_t)g * NK + k) * 8;
            so[0] = bv; so[1] = sx1; so[2] = sy1; so[3] = sx2; so[4] = sy2;
            so[5] = cls; so[6] = boi; so[7] = 0.0f;
        }
        float bx1 = __fadd_rn(sx1, tb), by1 = __fadd_rn(sy1, tb);
        float bx2 = __fadd_rn(sx2, tb), by2 = __fadd_rn(sy2, tb);
        float sar = __fmul_rn(__fsub_rn(bx2, bx1), __fsub_rn(by2, by1));
        for (int i = lane; i < NN; i += 64) {
            if (!((M[i >> 6] >> (i & 63)) & 1ull)) continue;
            float v = E[(size_t)i * 8 + 4];
            if (v == -INFINITY) continue;
            float ox1 = __fadd_rn(E[(size_t)i * 8 + 0], tb);
            float oy1 = __fadd_rn(E[(size_t)i * 8 + 1], tb);
            float ox2 = __fadd_rn(E[(size_t)i * 8 + 2], tb);
            float oy2 = __fadd_rn(E[(size_t)i * 8 + 3], tb);
            float oar = __fmul_rn(__fsub_rn(ox2, ox1), __fsub_rn(oy2, oy1));
            float ltx = fmaxf(ox1, bx1), lty = fmaxf(oy1, by1);
            float rbx = fminf(ox2, bx2), rby = fminf(oy2, by2);
            float wx = fmaxf(__fsub_rn(rbx, ltx), 0.0f);
            float wy = fmaxf(__fsub_rn(rby, lty), 0.0f);
            float inter = __fmul_rn(wx, wy);
            float den = __fsub_rn(__fadd_rn(oar, sar), inter);
            if ((double)inter > C_SUP * (double)den) E[(size_t)i * 8 + 4] = -INFINITY;
        }
        kout = k + 1;
    }
    if (lane == 0) selcnt[g] = kout;
}

template <int CAP>
__device__ __forceinline__ float selN(const float a[CAP], int j) {
    float r = a[0];
#pragma unroll
    for (int i = 1; i < CAP; ++i) r = (j == i) ? a[i] : r;
    return r;
}
__device__ __forceinline__ float rdlane(float v, int l) {
    return __uint_as_float(
        (unsigned)__builtin_amdgcn_readlane((int)__float_as_uint(v), l));
}
__device__ __forceinline__ unsigned long long rdlane64(unsigned long long v, int l) {
    unsigned lo = (unsigned)__builtin_amdgcn_readlane((int)(unsigned)v, l);
    unsigned hi = (unsigned)__builtin_amdgcn_readlane((int)(unsigned)(v >> 32), l);
    return ((unsigned long long)hi << 32) | lo;
}

// exact register sweep (fallback; identical semantics to round-10 main path)
template <int CAP>
__device__ __forceinline__ int sweep_reg(
    int lane, int n, float tb,
    const float* sx1, const float* sy1, const float* sx2, const float* sy2,
    int* acc)
{
    float ox1[CAP], oy1[CAP], ox2[CAP], oy2[CAP], oar[CAP];
    unsigned alive = 0;
#pragma unroll
    for (int j = 0; j < CAP; ++j) {
        int sidx = lane * CAP + j;
        if (sidx < n) {
            float a  = __fadd_rn(sx1[sidx], tb);
            float b_ = __fadd_rn(sy1[sidx], tb);
            float c_ = __fadd_rn(sx2[sidx], tb);
            float d_ = __fadd_rn(sy2[sidx], tb);
            ox1[j] = a; oy1[j] = b_; ox2[j] = c_; oy2[j] = d_;
            oar[j] = __fmul_rn(__fsub_rn(c_, a), __fsub_rn(d_, b_));
            alive |= 1u << j;
        } else {
            ox1[j] = 0.f; oy1[j] = 0.f; ox2[j] = 0.f; oy2[j] = 0.f; oar[j] = 0.f;
        }
    }
    int kout = 0;
    while (kout < NK) {
        unsigned long long bal = __ballot(alive != 0u);
        if (!bal) break;
        int fl = (int)__ffsll(bal) - 1;                           // uniform
        unsigned am = (unsigned)__builtin_amdgcn_readlane((int)alive, fl);
        int js = __ffs(am) - 1;                                   // uniform
        float bx1 = rdlane(selN<CAP>(ox1, js), fl);
        float by1 = rdlane(selN<CAP>(oy1, js), fl);
        float bx2 = rdlane(selN<CAP>(ox2, js), fl);
        float by2 = rdlane(selN<CAP>(oy2, js), fl);
        float bar = rdlane(selN<CAP>(oar, js), fl);
        if (lane == 0) acc[kout] = fl * CAP + js;
        kout++;
        unsigned kill = 0;
#pragma unroll
        for (int j = 0; j < CAP; ++j) {
            float ltx = fmaxf(ox1[j], bx1), lty = fmaxf(oy1[j], by1);
            float rbx = fminf(ox2[j], bx2), rby = fminf(oy2[j], by2);
            float wx = fmaxf(__fsub_rn(rbx, ltx), 0.0f);
            float wy = fmaxf(__fsub_rn(rby, lty), 0.0f);
            float inter = __fmul_rn(wx, wy);
            float den = __fsub_rn(__fadd_rn(oar[j], bar), inter);
            if ((double)inter > C_SUP * (double)den) kill |= 1u << j;
        }
        alive &= ~kill;
    }
    return kout;
}

// -- 512-thr: bitmask compaction + sort + ballot matrix + scalar sweep ------
__global__ __launch_bounds__(512) void bucket_nms_kernel(
    const unsigned long long* __restrict__ masks,
    float* __restrict__ entries,
    float* __restrict__ selbuf, int* __restrict__ selcnt)
{
    int g = blockIdx.x;
    int tid = threadIdx.x;
    float* E = entries + (size_t)g * NN * 8;
    const unsigned long long* M = masks + (size_t)g * NWRD_P;
    float cls = (float)(g % NCLS + 1);
    float tb = __fmul_rn(cls, 801.0f);

    __shared__ int sidx[PMAX];
    __shared__ int woff[NWRD + 1];
    __shared__ unsigned skhi[PMAX], sklo[PMAX];
    __shared__ int sperm[PMAX];
    __shared__ float sx1[PMAX], sy1[PMAX], sx2[PMAX], sy2[PMAX];
    __shared__ unsigned long long dmask[MATW * 4];   // 8 KB
    __shared__ int acc[NK];
    __shared__ int s_kout, s_fb;

    // phase 0: bitmask -> deterministic compaction (ascending slot order)
    unsigned long long myw = (tid < NWRD) ? M[tid] : 0ull;
    if (tid < NWRD) woff[tid] = __popcll(myw);
    __syncthreads();
    if (tid == 0) {
        int a = 0;
        for (int w = 0; w < NWRD; ++w) { int c = woff[w]; woff[w] = a; a += c; }
        woff[NWRD] = a;
    }
    __syncthreads();
    int n = woff[NWRD];
    if (n == 0) { if (tid == 0) selcnt[g] = 0; return; }
    if (n > PMAX) {   // never expected; exact sparse path
        if (tid < 64) nms_glb_sparse(g, M, E, tb, cls, selbuf, selcnt);
        return;
    }
    if (tid < NWRD) {
        unsigned long long m = myw;
        int base = woff[tid], r = 0;
        while (m) {
            int b = (int)__ffsll(m) - 1;
            sidx[base + r] = tid * 64 + b;
            r++; m &= m - 1;
        }
    }
    __syncthreads();

    int P = 64; while (P < n) P <<= 1;

    for (int i = tid; i < P; i += 512) {
        if (i < n) {
            const float2 kv = *reinterpret_cast<const float2*>(
                E + (size_t)sidx[i] * 8 + 4);
            skhi[i] = __float_as_uint(kv.x);
            sklo[i] = ~((unsigned)kv.y);   // u64 max == (score desc, idx asc)
        } else { skhi[i] = 0u; sklo[i] = 0u; }
        sperm[i] = i;
    }
    __syncthreads();
    // bitonic sort desc; j<128 stages wave-local
    for (int k = 2; k <= P; k <<= 1) {
        for (int j = k >> 1; j > 0; j >>= 1) {
            bool cross = (j >= 128);
            if (cross) __syncthreads();
            for (int t = tid; t < (P >> 1); t += 512) {
                int i = ((t & ~(j - 1)) << 1) | (t & (j - 1));
                int l = i | j;
                unsigned ah = skhi[i], al = sklo[i], ch = skhi[l], cl_ = sklo[l];
                bool alt = (ah < ch) || (ah == ch && al < cl_);
                bool agt = (ah > ch) || (ah == ch && al > cl_);
                bool sw = ((i & k) == 0) ? alt : agt;
                if (sw) {
                    skhi[i] = ch; sklo[i] = cl_; skhi[l] = ah; sklo[l] = al;
                    int tp = sperm[i]; sperm[i] = sperm[l]; sperm[l] = tp;
                }
            }
            if (cross) __syncthreads();
            else CFENCE();
        }
    }
    __syncthreads();
    // stage RAW coords in sorted order (one 16B load per entry)
    for (int i = tid; i < n; i += 512) {
        const float4 v = *reinterpret_cast<const float4*>(
            E + (size_t)sidx[sperm[i]] * 8);
        sx1[i] = v.x; sy1[i] = v.y; sx2[i] = v.z; sy2[i] = v.w;
    }
    __syncthreads();

    int W = (n < MATW) ? n : MATW;
    int nchunk = (W + 63) >> 6;
    int wv = tid >> 6, lane = tid & 63;

    // j-chunk boxes (offset coords) in registers
    float jx1[4], jy1[4], jx2[4], jy2[4], jar[4];
#pragma unroll
    for (int c = 0; c < 4; ++c) {
        int j = c * 64 + lane;
        if (j < W) {
            float a  = __fadd_rn(sx1[j], tb);
            float b_ = __fadd_rn(sy1[j], tb);
            float c_ = __fadd_rn(sx2[j], tb);
            float d_ = __fadd_rn(sy2[j], tb);
            jx1[c] = a; jy1[c] = b_; jx2[c] = c_; jy2[c] = d_;
            jar[c] = __fmul_rn(__fsub_rn(c_, a), __fsub_rn(d_, b_));
        } else {
            jx1[c] = 0.f; jy1[c] = 0.f; jx2[c] = 0.f; jy2[c] = 0.f; jar[c] = 0.f;
        }
    }
    // matrix rows striped across 8 waves; uniform LDS row read + prefetch
    {
        int i0 = wv;
        float nx1 = 0.f, ny1 = 0.f, nx2 = 0.f, ny2 = 0.f;
        if (i0 < W) { nx1 = sx1[i0]; ny1 = sy1[i0]; nx2 = sx2[i0]; ny2 = sy2[i0]; }
        for (int i = i0; i < W; i += 8) {
            float rx1 = nx1, ry1 = ny1, rx2 = nx2, ry2 = ny2;
            int ni = i + 8;
            if (ni < W) { nx1 = sx1[ni]; ny1 = sy1[ni]; nx2 = sx2[ni]; ny2 = sy2[ni]; }
            float bx1 = __fadd_rn(rx1, tb), by1 = __fadd_rn(ry1, tb);
            float bx2 = __fadd_rn(rx2, tb), by2 = __fadd_rn(ry2, tb);
            float bar = __fmul_rn(__fsub_rn(bx2, bx1), __fsub_rn(by2, by1));
            int ic = i >> 6;
#pragma unroll
            for (int c = 0; c < 4; ++c) {
                if (c >= ic && c < nchunk) {
                    bool jv = (c * 64 + lane) < W;
                    float ltx = fmaxf(jx1[c], bx1), lty = fmaxf(jy1[c], by1);
                    float rbx = fminf(jx2[c], bx2), rby = fminf(jy2[c], by2);
                    float wx = fmaxf(__fsub_rn(rbx, ltx), 0.0f);
                    float wy = fmaxf(__fsub_rn(rby, lty), 0.0f);
                    float inter = __fmul_rn(wx, wy);
                    float den = __fsub_rn(__fadd_rn(jar[c], bar), inter);
                    bool sup = jv && ((double)inter > C_SUP * (double)den);
                    unsigned long long w64 = __ballot(sup);
                    if (lane == 0) dmask[i * 4 + c] = w64;
                }
            }
        }
    }
    __syncthreads();

    // SCALAR bit sweep on wave 0 (wave-uniform alive words)
    if (tid < 64) {
        unsigned long long a0 = 0, a1 = 0, a2 = 0, a3 = 0;
        {
            int rem = W;
            a0 = (rem >= 64) ? ~0ull : ((rem > 0) ? ((1ull << rem) - 1) : 0); rem -= 64;
            a1 = (rem >= 64) ? ~0ull : ((rem > 0) ? ((1ull << rem) - 1) : 0); rem -= 64;
            a2 = (rem >= 64) ? ~0ull : ((rem > 0) ? ((1ull << rem) - 1) : 0); rem -= 64;
            a3 = (rem >= 64) ? ~0ull : ((rem > 0) ? ((1ull << rem) - 1) : 0);
        }
        int kout = 0;
        while (kout < NK) {
            int cand;
            if      (a0) cand = (int)__ffsll(a0) - 1;
            else if (a1) cand = 64  + (int)__ffsll(a1) - 1;
            else if (a2) cand = 128 + (int)__ffsll(a2) - 1;
            else if (a3) cand = 192 + (int)__ffsll(a3) - 1;
            else break;
            if (lane == 0) acc[kout] = cand;
            kout++;
            unsigned long long mrow = (lane < 4) ? dmask[cand * 4 + lane] : 0ull;
            a0 &= ~rdlane64(mrow, 0);
            a1 &= ~rdlane64(mrow, 1);
            a2 &= ~rdlane64(mrow, 2);
            a3 &= ~rdlane64(mrow, 3);
        }
        if (lane == 0) {
            s_kout = kout;
            s_fb = (kout < NK && n > W) ? 1 : 0;   // prefix exhausted early
        }
    }
    __syncthreads();

    if (s_fb) {
        // exact fallback (rare): redo from scratch with the register sweep
        if (tid < 64) {
            int kout = sweep_reg<8>(lane, n, tb, sx1, sy1, sx2, sy2, acc);
            if (lane == 0) s_kout = kout;
        }
        __syncthreads();
    }

    int kc = s_kout;
    if (tid == 0) selcnt[g] = kc;
    for (int k = tid; k < kc; k += 512) {
        int cand = acc[k];
        float* so = selbuf + ((size_t)g * NK + k) * 8;
        so[0] = __uint_as_float(skhi[cand]);
        so[1] = sx1[cand]; so[2] = sy1[cand];
        so[3] = sx2[cand]; so[4] = sy2[cand];
        so[5] = cls; so[6] = (float)(~sklo[cand]); so[7] = 0.0f;
    }
}

// ------ merge: exact parallel top-K via LB bound (unchanged from r13) ------
__global__ __launch_bounds__(512) void merge_kernel(
    const float* __restrict__ selbuf, const int* __restrict__ selcnt,
    float* __restrict__ out_dets, float* __restrict__ out_kl)
{
    int b = blockIdx.x, tid = threadIdx.x;
    __shared__ int scnt[NCLS], soff[NCLS + 1];
    __shared__ unsigned akhi[512], aklo[512];
    __shared__ unsigned bkhi[MPB], bklo[MPB], bpay[MPB];
    __shared__ int s_T, s_cntA;
    __shared__ unsigned s_LBhi, s_LBlo;

    if (tid < NCLS) scnt[tid] = selcnt[b * NCLS + tid];
    if (tid == 0) s_T = 0;
    __syncthreads();
    if (tid == 0) {
        int a = 0, ca = 0;
        for (int c = 0; c < NCLS; ++c) {
            soff[c] = a; a += scnt[c];
            ca += (scnt[c] < 4 ? scnt[c] : 4);
        }
        soff[NCLS] = a; s_cntA = ca;
    }
    __syncthreads();
    int tot = soff[NCLS];

    if (tot == 0) {
        for (int z = tid; z < NK * 5; z += 512) out_dets[(size_t)b * NK * 5 + z] = 0.0f;
        for (int z = tid; z < NK; z += 512)     out_kl[(size_t)b * NK + z] = -1.0f;
        return;
    }

    {
        unsigned kh = 0u, kl = 0u;
        if (tid < NCLS * 4) {
            int c = tid >> 2, i = tid & 3;
            if (i < scnt[c]) {
                const float* e = selbuf + ((size_t)(b * NCLS + c) * NK + i) * 8;
                kh = __float_as_uint(e[0]); kl = ~((unsigned)e[6]);
            }
        }
        akhi[tid] = kh; aklo[tid] = kl;
    }
    __syncthreads();
    for (int k = 2; k <= 512; k <<= 1) {
        for (int j = k >> 1; j > 0; j >>= 1) {
            bool cross = (j >= 128);
            if (cross) __syncthreads();
            if (tid < 256) {
                int t = tid;
                int i = ((t & ~(j - 1)) << 1) | (t & (j - 1));
                int l = i | j;
                unsigned ah = akhi[i], al = aklo[i], ch = akhi[l], cl_ = aklo[l];
                bool alt = (ah < ch) || (ah == ch && al < cl_);
                bool agt = (ah > ch) || (ah == ch && al > cl_);
                bool sw = ((i & k) == 0) ? alt : agt;
                if (sw) {
                    akhi[i] = ch; aklo[i] = cl_; akhi[l] = ah; aklo[l] = al;
                }
            }
            if (cross) __syncthreads();
            else CFENCE();
        }
    }
    __syncthreads();
    if (tid == 0) {
        if (s_cntA >= NK) { s_LBhi = akhi[NK - 1]; s_LBlo = aklo[NK - 1]; }
        else              { s_LBhi = 0u;           s_LBlo = 0u; }
    }
    __syncthreads();
    unsigned LBhi = s_LBhi, LBlo = s_LBlo;

    for (int flat = tid; flat < tot; flat += 512) {
        int lo = 0, hi = NCLS - 1;
        while (lo < hi) { int mid = (lo + hi + 1) >> 1;
                          if (soff[mid] <= flat) lo = mid; else hi = mid - 1; }
        int c = lo, i = flat - soff[c];
        const float* e = selbuf + ((size_t)(b * NCLS + c) * NK + i) * 8;
        unsigned kh = __float_as_uint(e[0]), kl = ~((unsigned)e[6]);
        bool ge = (kh > LBhi) || (kh == LBhi && kl >= LBlo);
        if (ge) {
            int pos = atomicAdd(&s_T, 1);
            if (pos < MPB) { bkhi[pos] = kh; bklo[pos] = kl;
                             bpay[pos] = (unsigned)((c << 7) | i); }
        }
    }
    __syncthreads();
    int T = s_T;

    if (T > MPB) {
        if (tid >= 64) return;
        int lane = tid;
        int g0 = b * NCLS + lane;
        int g1 = (lane < NCLS - 64) ? g0 + 64 : -1;
        int c0 = scnt[lane];
        int c1 = (g1 >= 0) ? scnt[lane + 64] : 0;
        int p0 = 0, p1 = 0;
        unsigned long long k0c = 0, k1c = 0;
        if (p0 < c0) { const float* h = selbuf + ((size_t)g0 * NK) * 8;
            k0c = ((unsigned long long)__float_as_uint(h[0]) << 32) | (unsigned long long)(~(unsigned)h[6]); }
        if (g1 >= 0 && p1 < c1) { const float* h = selbuf + ((size_t)g1 * NK) * 8;
            k1c = ((unsigned long long)__float_as_uint(h[0]) << 32) | (unsigned long long)(~(unsigned)h[6]); }
        for (int k = 0; k < NK; ++k) {
            bool t1 = (k1c > k0c);
            unsigned long long bk = t1 ? k1c : k0c;
            int bslot = t1 ? (lane + 64) : lane;
            for (int o = 1; o < 64; o <<= 1) {
                unsigned long long k2 = __shfl_xor(bk, o);
                int b2 = __shfl_xor(bslot, o);
                if (k2 > bk) { bk = k2; bslot = b2; }
            }
            if (bk == 0ull) {
                for (int z = k * 5 + lane; z < NK * 5; z += 64)
                    out_dets[(size_t)b * NK * 5 + z] = 0.0f;
                for (int z = k + lane; z < NK; z += 64)
                    out_kl[(size_t)b * NK + z] = -1.0f;
                return;
            }
            int owner = bslot & 63;
            if (lane == owner) {
                bool isA = (bslot < 64);
                int gg = isA ? g0 : g1;
                int pp = isA ? p0 : p1;
                const float* e = selbuf + ((size_t)gg * NK + pp) * 8;
                size_t o = ((size_t)b * NK + k) * 5;
                out_dets[o + 0] = e[1]; out_dets[o + 1] = e[2];
                out_dets[o + 2] = e[3]; out_dets[o + 3] = e[4];
                out_dets[o + 4] = e[0];
                out_kl[(size_t)b * NK + k] = e[5];
                if (isA) {
                    p0++; k0c = 0;
                    if (p0 < c0) { const float* h = selbuf + ((size_t)g0 * NK + p0) * 8;
                        k0c = ((unsigned long long)__float_as_uint(h[0]) << 32) | (unsigned long long)(~(unsigned)h[6]); }
                } else {
                    p1++; k1c = 0;
                    if (p1 < c1) { const float* h = selbuf + ((size_t)g1 * NK + p1) * 8;
                        k1c = ((unsigned long long)__float_as_uint(h[0]) << 32) | (unsigned long long)(~(unsigned)h[6]); }
                }
            }
        }
        return;
    }

    int P = 128; while (P < T) P <<= 1;
    for (int i = T + tid; i < P; i += 512) { bkhi[i] = 0u; bklo[i] = 0u; bpay[i] = 0u; }
    __syncthreads();
    for (int k = 2; k <= P; k <<= 1) {
        for (int j = k >> 1; j > 0; j >>= 1) {
            bool cross = (j >= 128);
            if (cross) __syncthreads();
            for (int t = tid; t < (P >> 1); t += 512) {
                int i = ((t & ~(j - 1)) << 1) | (t & (j - 1));
                int l = i | j;
                unsigned ah = bkhi[i], al = bklo[i], ch = bkhi[l], cl_ = bklo[l];
                bool alt = (ah < ch) || (ah == ch && al < cl_);
                bool agt = (ah > ch) || (ah == ch && al > cl_);
                bool sw = ((i & k) == 0) ? alt : agt;
                if (sw) {
                    bkhi[i] = ch; bklo[i] = cl_; bkhi[l] = ah; bklo[l] = al;
                    unsigned tp = bpay[i]; bpay[i] = bpay[l]; bpay[l] = tp;
                }
            }
            if (cross) __syncthreads();
            else CFENCE();
        }
    }
    __syncthreads();
    int kc = (T < NK) ? T : NK;
    for (int k = tid; k < NK; k += 512) {
        size_t o = ((size_t)b * NK + k) * 5;
        if (k < kc) {
            unsigned pay = bpay[k];
            int c = (int)(pay >> 7), p = (int)(pay & 127);
            const float* e = selbuf + ((size_t)(b * NCLS + c) * NK + p) * 8;
            out_dets[o + 0] = e[1]; out_dets[o + 1] = e[2];
            out_dets[o + 2] = e[3]; out_dets[o + 3] = e[4];
            out_dets[o + 4] = e[0];
            out_kl[(size_t)b * NK + k] = e[5];
        } else {
            out_dets[o + 0] = 0.0f; out_dets[o + 1] = 0.0f;
            out_dets[o + 2] = 0.0f; out_dets[o + 3] = 0.0f;
            out_dets[o + 4] = 0.0f;
            out_kl[(size_t)b * NK + k] = -1.0f;
        }
    }
}

extern "C" void kernel_launch(void* const* d_in, const int* in_sizes, int n_in,
                              void* d_out, int out_size, void* d_ws, size_t ws_size,
                              hipStream_t stream) {
    const float* logits = (const float*)d_in[0];
    const float* reg    = (const float*)d_in[1];
    const float* props  = (const float*)d_in[2];
    const float* gtb    = (const float*)d_in[3];
    const int*   gtl    = (const int*)d_in[4];

    float* out          = (float*)d_out;
    float* out_dets     = out;                    // NB*NK*5 = 2000
    float* out_kl       = out + NB * NK * 5;      // NB*NK   = 400
    float* out_assigned = out_kl + NB * NK;       // NB*NN   = 24000
    float* out_matched  = out_assigned + NB * NN; // NB*NN   = 24000

    char* ws = (char*)d_ws;
    int*   selcnt  = (int*)(ws + 0);                        // 1440 B
    float* selbuf  = (float*)(ws + 65536);                  // 1152000 B
    unsigned long long* masks =
        (unsigned long long*)(ws + 2097152);                // 360*96*8 = 276480 B
    float* entries = (float*)(ws + 8388608);                // 360*6000*32B = 69.1 MB

    hipMemsetAsync(masks, 0, (size_t)NBUC * NWRD_P * sizeof(unsigned long long),
                   stream);
    const int MATCH_BLOCKS = (NB * NN + 255) / 256;   // 94
    fused_kernel<<<RS_BLOCKS + MATCH_BLOCKS, 256, 0, stream>>>(
        logits, reg, props, gtb, gtl, out_assigned, out_matched,
        masks, entries);
    bucket_nms_kernel<<<NBUC, 512, 0, stream>>>(
        masks, entries, selbuf, selcnt);
    merge_kernel<<<NB, 512, 0, stream>>>(selbuf, selcnt, out_dets, out_kl);
}